// Round 19
// baseline (237.164 us; speedup 1.0000x reference)
//
#include <hip/hip_runtime.h>
#include <hip/hip_fp16.h>

// ---------------------------------------------------------------------------
// GCN 3-layer forward on MI355X.  (r19: k_fill write-bounce fix)
// init+splitW -> deg -> scan1(+dinv) -> scan23(offs + inclusive sctr in deg)
//   -> fill (ONE atomic + NONTEMPORAL csr store) -> per layer:
//   L1: k_gemm_bf16 (bf16x3, LDS-staged) -> k_agg128 (y1 fp16, 8-edge unroll)
//   L2: k_gemm2 (A fp16 exact, W fp16-split) -> k_agg64y
//   L3: k_gemm3 -> k_agg64out (f32 d_out)
// r18 post-mortem: k_fill = 60us top dispatch; WRITE_SIZE 56MB for 3.2MB of
// csr (64B-line inter-XCD ping-pong on scattered 4B writes). Fix: nt-store
// (no RFO/L2 ownership) + fused slot counter (one random atomic, not two).
// ---------------------------------------------------------------------------

typedef __attribute__((ext_vector_type(8))) short bf16x8;
typedef __attribute__((ext_vector_type(8))) _Float16 f16x8;
typedef __attribute__((ext_vector_type(4))) float f32x4;
typedef unsigned short u16;
typedef unsigned int u32;

static inline size_t alignup(size_t v, size_t a) { return (v + a - 1) & ~(a - 1); }

__device__ __forceinline__ u32 pack_hi16(u32 b0, u32 b1) {
    return __builtin_amdgcn_perm(b1, b0, 0x07060302u);   // top16(b0)|top16(b1)
}

// --- W1 split: fragment-ordered bf16 hi/lo -----------------------------------
__device__ __forceinline__ void splitW_bf16(const float* __restrict__ W,
                                            u16* __restrict__ Wh,
                                            u16* __restrict__ Wl, int s, int F) {
    int c = s % F;
    int kb = (s / F) * 8;
    union { u32 u[4]; bf16x8 v; } hi, lo;
#pragma unroll
    for (int p = 0; p < 4; p++) {
        float x0 = W[(size_t)(kb + 2 * p) * F + c];
        float x1 = W[(size_t)(kb + 2 * p + 1) * F + c];
        u32 b0 = __float_as_uint(x0), b1 = __float_as_uint(x1);
        float l0 = x0 - __uint_as_float(b0 & 0xFFFF0000u);
        float l1 = x1 - __uint_as_float(b1 & 0xFFFF0000u);
        hi.u[p] = pack_hi16(b0, b1);
        lo.u[p] = pack_hi16(__float_as_uint(l0), __float_as_uint(l1));
    }
    *(bf16x8*)(Wh + (size_t)s * 8) = hi.v;
    *(bf16x8*)(Wl + (size_t)s * 8) = lo.v;
}

// --- W2/W3 split: fragment-ordered fp16 hi/lo (22-bit effective) -------------
__device__ __forceinline__ void splitW_f16(const float* __restrict__ W,
                                           u16* __restrict__ Wh,
                                           u16* __restrict__ Wl, int s, int F) {
    int c = s % F;
    int kb = (s / F) * 8;
    union { u16 u[8]; bf16x8 v; } hi, lo;
#pragma unroll
    for (int p = 0; p < 8; p++) {
        float xv = W[(size_t)(kb + p) * F + c];
        __half h = __float2half(xv);
        __half l = __float2half(xv - __half2float(h));
        hi.u[p] = __half_as_ushort(h);
        lo.u[p] = __half_as_ushort(l);
    }
    *(bf16x8*)(Wh + (size_t)s * 8) = hi.v;
    *(bf16x8*)(Wl + (size_t)s * 8) = lo.v;
}

// --- init (zero deg + detect layout) fused with W splits ---------------------
__global__ void k_init_split(const int* __restrict__ ei, int* __restrict__ flag,
                             int* __restrict__ deg, int N, int nb,
                             const float* __restrict__ W1, u16* w1h, u16* w1l,
                             const float* __restrict__ W2, u16* w2h, u16* w2l,
                             const float* __restrict__ W3, u16* w3h, u16* w3l) {
    int b = blockIdx.x;
    if (b < nb) {
        int i = b * 256 + threadIdx.x;
        if (i < N) deg[i] = 0;
        if (b == 0 && threadIdx.x < 64) {
            int v = ei[2 * threadIdx.x + 1];          // high word if int64
            unsigned long long m = __ballot(v != 0);
            if (threadIdx.x == 0) *flag = (m == 0ull) ? 1 : 0;
        }
        return;
    }
    int s = (b - nb) * 256 + threadIdx.x;
    if (s < 8192) splitW_bf16(W1, w1h, w1l, s, 128);              // 512x128/8
    else if (s < 9216) splitW_f16(W2, w2h, w2l, s - 8192, 64);    // 128x64/8
    else if (s < 9728) splitW_f16(W3, w3h, w3l, s - 9216, 64);    // 64x64/8
}

__global__ void k_deg(const int* __restrict__ ei, int E,
                      const int* __restrict__ flag, int* __restrict__ deg) {
    int i = blockIdx.x * blockDim.x + threadIdx.x;
    if (i >= E) return;
    int is64 = *flag;
    int d = is64 ? ei[2 * (E + i)] : ei[E + i];
    atomicAdd(&deg[d], 1);
}

__global__ void k_scan1(const int* __restrict__ deg, int* __restrict__ offs,
                        int* __restrict__ bsums, float* __restrict__ dinv, int N) {
    __shared__ int s[256];
    int i = blockIdx.x * 256 + threadIdx.x;
    int v = (i < N) ? deg[i] : 0;
    if (i < N) dinv[i] = rsqrtf((float)v + 1.0f);
    s[threadIdx.x] = v;
    __syncthreads();
    for (int off = 1; off < 256; off <<= 1) {
        int t = (threadIdx.x >= off) ? s[threadIdx.x - off] : 0;
        __syncthreads();
        s[threadIdx.x] += t;
        __syncthreads();
    }
    if (i < N) offs[i] = s[threadIdx.x] - v;   // exclusive
    if (threadIdx.x == 255) bsums[blockIdx.x] = s[255];
}

// scan23: finalize exclusive offs AND convert deg[] in place to the INCLUSIVE
// offset (slot countdown counter for k_fill): deg[i] <- offs[i] + deg[i].
__global__ void k_scan23(int* __restrict__ offs, const int* __restrict__ bsums,
                         int* __restrict__ deg, int nb, int N, int E) {
    __shared__ int s[256];
    int tid = threadIdx.x;
    s[tid] = (tid < nb) ? bsums[tid] : 0;
    __syncthreads();
    for (int off = 1; off < 256; off <<= 1) {
        int t = (tid >= off) ? s[tid - off] : 0;
        __syncthreads();
        s[tid] += t;                 // inclusive scan
        __syncthreads();
    }
    int boff = (blockIdx.x > 0) ? s[blockIdx.x - 1] : 0;
    int i = blockIdx.x * 256 + tid;
    if (i < N) {
        int o = offs[i] + boff;
        offs[i] = o;
        deg[i] += o;                 // inclusive end = countdown start
    }
    if (i == 0) offs[N] = E;
}

// --- CSR fill: ONE random atomic (fused slot counter) + NONTEMPORAL store ----
__global__ void k_fill(const int* __restrict__ ei, int E,
                       const int* __restrict__ flag,
                       int* __restrict__ sctr, int* __restrict__ csr) {
    int i = blockIdx.x * blockDim.x + threadIdx.x;
    if (i >= E) return;
    int is64 = *flag;
    int s = is64 ? ei[2 * i] : ei[i];
    int d = is64 ? ei[2 * (E + i)] : ei[E + i];
    int slot = atomicSub(&sctr[d], 1) - 1;
    __builtin_nontemporal_store(s, &csr[slot]);   // no L2 RFO / line bounce
}

// --- L1 GEMM: H'[N,128] = dinv * (X[N,512] @ W1), bf16x3, fp16 out -----------
__global__ __launch_bounds__(128) void k_gemm_bf16(
        const float* __restrict__ X,
        const u16* __restrict__ Wh, const u16* __restrict__ Wl,
        const float* __restrict__ dinv, __half* __restrict__ Hh, int N) {
    constexpr int K = 512, F = 128, MF = 4, NF = 4, NT = K / 32;
    __shared__ float4 smemA[2][512];   // 2 x 8 KB

    const int tid = threadIdx.x;
    const int lane = tid & 63;
    const int w = tid >> 6;
    const int colbase = w * (NF * 16);
    const int lg = lane >> 4, li = lane & 15;
    const int row0 = blockIdx.x * 64;

    auto stage = [&](int b, int t) {
#pragma unroll
        for (int j = 0; j < 4; j++) {
            int c_lin = j * 128 + tid;
            int row = c_lin >> 3, c = c_lin & 7;
            int rg = row0 + row;
            if (rg >= N) rg = N - 1;
            int cs = c ^ (row & 7);
            const float* g = X + (size_t)rg * K + t * 32 + cs * 4;
            char* l = (char*)&smemA[b][0] + j * 2048 + w * 1024;
            __builtin_amdgcn_global_load_lds(
                (const __attribute__((address_space(1))) void*)g,
                (__attribute__((address_space(3))) void*)l, 16, 0, 0);
        }
    };

    f32x4 acc[MF][NF];
#pragma unroll
    for (int m = 0; m < MF; m++)
#pragma unroll
        for (int n = 0; n < NF; n++) acc[m][n] = (f32x4){0.f, 0.f, 0.f, 0.f};

    stage(0, 0);
    __syncthreads();

    for (int t = 0; t < NT; t++) {
        const int b = t & 1;
        bf16x8 bh[NF], bl[NF];
        size_t slot0 = (size_t)(t * 4 + lg) * F + colbase + li;
#pragma unroll
        for (int n = 0; n < NF; n++) {
            bh[n] = *(const bf16x8*)(Wh + (slot0 + n * 16) * 8);
            bl[n] = *(const bf16x8*)(Wl + (slot0 + n * 16) * 8);
        }
        __builtin_amdgcn_sched_barrier(0);
        if (t + 1 < NT) stage(b ^ 1, t + 1);
        const float4* lt = &smemA[b][0];
        bf16x8 ah[MF], al[MF];
#pragma unroll
        for (int m = 0; m < MF; m++) {
            int row = m * 16 + li;
            int base = row * 8, sw = row & 7;
            float4 c0 = lt[base + ((2 * lg) ^ sw)];
            float4 c1 = lt[base + ((2 * lg + 1) ^ sw)];
            float xv[8] = {c0.x, c0.y, c0.z, c0.w, c1.x, c1.y, c1.z, c1.w};
            union { u32 u[4]; bf16x8 v; } hi, lo;
#pragma unroll
            for (int q = 0; q < 4; q++) {
                u32 b0 = __float_as_uint(xv[2 * q]);
                u32 b1 = __float_as_uint(xv[2 * q + 1]);
                float l0 = xv[2 * q]     - __uint_as_float(b0 & 0xFFFF0000u);
                float l1 = xv[2 * q + 1] - __uint_as_float(b1 & 0xFFFF0000u);
                hi.u[q] = pack_hi16(b0, b1);
                lo.u[q] = pack_hi16(__float_as_uint(l0), __float_as_uint(l1));
            }
            ah[m] = hi.v;
            al[m] = lo.v;
        }
#pragma unroll
        for (int m = 0; m < MF; m++)
#pragma unroll
            for (int n = 0; n < NF; n++) {
                acc[m][n] = __builtin_amdgcn_mfma_f32_16x16x32_bf16(ah[m], bh[n], acc[m][n], 0, 0, 0);
                acc[m][n] = __builtin_amdgcn_mfma_f32_16x16x32_bf16(ah[m], bl[n], acc[m][n], 0, 0, 0);
                acc[m][n] = __builtin_amdgcn_mfma_f32_16x16x32_bf16(al[m], bh[n], acc[m][n], 0, 0, 0);
            }
        __syncthreads();
    }

#pragma unroll
    for (int m = 0; m < MF; m++) {
        int rb = row0 + m * 16 + lg * 4;
#pragma unroll
        for (int r = 0; r < 4; r++) {
            int gr = rb + r;
            if (gr >= N) continue;
            float di = dinv[gr];
#pragma unroll
            for (int n = 0; n < NF; n++) {
                int col = colbase + n * 16 + li;
                Hh[(size_t)gr * F + col] = __float2half(acc[m][n][r] * di);
            }
        }
    }
}

// --- L2/L3 GEMM body: H'[N,64] = dinv * (Y[N,K] @ W), Y fp16 EXACT -----------
template <int K>
__device__ __forceinline__ void gemm_f16_body(
        const __half* __restrict__ Y,
        const u16* __restrict__ Wh, const u16* __restrict__ Wl,
        const float* __restrict__ dinv, __half* __restrict__ Hh, int N) {
    constexpr int F = 64, MF = 4, NF = 2, NT = K / 32;
    __shared__ float4 smemA[2][256];   // 2 x 4 KB

    const int tid = threadIdx.x;
    const int lane = tid & 63;
    const int w = tid >> 6;
    const int colbase = w * (NF * 16);
    const int lg = lane >> 4, li = lane & 15;
    const int row0 = blockIdx.x * 64;

    auto stage = [&](int b, int t) {
#pragma unroll
        for (int j = 0; j < 2; j++) {
            int c_lin = j * 128 + tid;          // 0..255
            int row = c_lin >> 2, c = c_lin & 3;
            int rg = row0 + row;
            if (rg >= N) rg = N - 1;
            int cs = c ^ (row & 3);
            const __half* g = Y + (size_t)rg * K + t * 32 + cs * 8;  // 16 B
            char* l = (char*)&smemA[b][0] + j * 2048 + w * 1024;
            __builtin_amdgcn_global_load_lds(
                (const __attribute__((address_space(1))) void*)g,
                (__attribute__((address_space(3))) void*)l, 16, 0, 0);
        }
    };

    f32x4 acc[MF][NF];
#pragma unroll
    for (int m = 0; m < MF; m++)
#pragma unroll
        for (int n = 0; n < NF; n++) acc[m][n] = (f32x4){0.f, 0.f, 0.f, 0.f};

    stage(0, 0);
    __syncthreads();

    for (int t = 0; t < NT; t++) {
        const int b = t & 1;
        f16x8 bh[NF], bl[NF];
        size_t slot0 = (size_t)(t * 4 + lg) * F + colbase + li;
#pragma unroll
        for (int n = 0; n < NF; n++) {
            bh[n] = *(const f16x8*)(Wh + (slot0 + n * 16) * 8);
            bl[n] = *(const f16x8*)(Wl + (slot0 + n * 16) * 8);
        }
        __builtin_amdgcn_sched_barrier(0);
        if (t + 1 < NT) stage(b ^ 1, t + 1);
        const float4* lt = &smemA[b][0];
        f16x8 a[MF];
#pragma unroll
        for (int m = 0; m < MF; m++) {
            int row = m * 16 + li;
            union { float4 f; f16x8 h; } u;
            u.f = lt[row * 4 + (lg ^ (row & 3))];
            a[m] = u.h;
        }
#pragma unroll
        for (int m = 0; m < MF; m++)
#pragma unroll
            for (int n = 0; n < NF; n++) {
                acc[m][n] = __builtin_amdgcn_mfma_f32_16x16x32_f16(a[m], bh[n], acc[m][n], 0, 0, 0);
                acc[m][n] = __builtin_amdgcn_mfma_f32_16x16x32_f16(a[m], bl[n], acc[m][n], 0, 0, 0);
            }
        __syncthreads();
    }

#pragma unroll
    for (int m = 0; m < MF; m++) {
        int rb = row0 + m * 16 + lg * 4;
#pragma unroll
        for (int r = 0; r < 4; r++) {
            int gr = rb + r;
            if (gr >= N) continue;
            float di = dinv[gr];
#pragma unroll
            for (int n = 0; n < NF; n++) {
                int col = colbase + n * 16 + li;
                Hh[(size_t)gr * F + col] = __float2half(acc[m][n][r] * di);
            }
        }
    }
}

__global__ __launch_bounds__(128) void k_gemm2(
        const __half* __restrict__ Y, const u16* __restrict__ Wh,
        const u16* __restrict__ Wl, const float* __restrict__ dinv,
        __half* __restrict__ Hh, int N) {
    gemm_f16_body<128>(Y, Wh, Wl, dinv, Hh, N);
}
__global__ __launch_bounds__(128) void k_gemm3(
        const __half* __restrict__ Y, const u16* __restrict__ Wh,
        const u16* __restrict__ Wl, const float* __restrict__ dinv,
        __half* __restrict__ Hh, int N) {
    gemm_f16_body<64>(Y, Wh, Wl, dinv, Hh, N);
}

// --- agg, F=128, fp16 H' in, fp16 y out (leaky-relu); 8-edge unroll -----------
__global__ __launch_bounds__(256) void k_agg128(const __half* __restrict__ Hh,
                                                const int* __restrict__ offs,
                                                const int* __restrict__ csr,
                                                const float* __restrict__ dinv,
                                                const float* __restrict__ bias,
                                                __half* __restrict__ Y, int N) {
    int node = blockIdx.x * 4 + (threadIdx.x >> 6);
    int lane = threadIdx.x & 63;
    if (node >= N) return;
    const __half2* H2 = (const __half2*)Hh;   // row = 64 half2
    float ax = 0.f, ay = 0.f;
    int o0 = offs[node], o1 = offs[node + 1];
    int e = o0;
    for (; e + 8 <= o1; e += 8) {
        int s[8];
#pragma unroll
        for (int q = 0; q < 8; q++) s[q] = csr[e + q];
        float2 f[8];
#pragma unroll
        for (int q = 0; q < 8; q++)
            f[q] = __half22float2(H2[(size_t)s[q] * 64 + lane]);
#pragma unroll
        for (int q = 0; q < 8; q++) { ax += f[q].x; ay += f[q].y; }
    }
    for (; e + 4 <= o1; e += 4) {
        int s0 = csr[e], s1 = csr[e + 1], s2 = csr[e + 2], s3 = csr[e + 3];
        float2 f0 = __half22float2(H2[(size_t)s0 * 64 + lane]);
        float2 f1 = __half22float2(H2[(size_t)s1 * 64 + lane]);
        float2 f2 = __half22float2(H2[(size_t)s2 * 64 + lane]);
        float2 f3 = __half22float2(H2[(size_t)s3 * 64 + lane]);
        ax += (f0.x + f1.x) + (f2.x + f3.x);
        ay += (f0.y + f1.y) + (f2.y + f3.y);
    }
    for (; e < o1; ++e) {
        float2 f0 = __half22float2(H2[(size_t)csr[e] * 64 + lane]);
        ax += f0.x; ay += f0.y;
    }
    float2 fs = __half22float2(H2[(size_t)node * 64 + lane]);
    float di = dinv[node];
    float2 bv = ((const float2*)bias)[lane];
    float vx = di * (ax + fs.x) + bv.x;
    float vy = di * (ay + fs.y) + bv.y;
    vx = vx > 0.f ? vx : 0.2f * vx;
    vy = vy > 0.f ? vy : 0.2f * vy;
    ((__half2*)Y)[(size_t)node * 64 + lane] = __floats2half2_rn(vx, vy);
}

// --- agg, F=64, fp16 H' in — shared body, fp16-y or f32-out; 8-edge unroll ----
template <bool RELU, bool OUT16>
__device__ __forceinline__ void agg64_body(const __half* __restrict__ Hh,
                                           const int* __restrict__ offs,
                                           const int* __restrict__ csr,
                                           const float* __restrict__ dinv,
                                           const float* __restrict__ bias,
                                           void* __restrict__ Y, int N) {
    int node = blockIdx.x * 8 + (threadIdx.x >> 5);
    int lane = threadIdx.x & 31;
    if (node >= N) return;
    const __half2* H2 = (const __half2*)Hh;   // row = 32 half2
    float ax = 0.f, ay = 0.f;
    int o0 = offs[node], o1 = offs[node + 1];
    int e = o0;
    for (; e + 8 <= o1; e += 8) {
        int s[8];
#pragma unroll
        for (int q = 0; q < 8; q++) s[q] = csr[e + q];
        float2 f[8];
#pragma unroll
        for (int q = 0; q < 8; q++)
            f[q] = __half22float2(H2[(size_t)s[q] * 32 + lane]);
#pragma unroll
        for (int q = 0; q < 8; q++) { ax += f[q].x; ay += f[q].y; }
    }
    for (; e + 4 <= o1; e += 4) {
        int s0 = csr[e], s1 = csr[e + 1], s2 = csr[e + 2], s3 = csr[e + 3];
        float2 f0 = __half22float2(H2[(size_t)s0 * 32 + lane]);
        float2 f1 = __half22float2(H2[(size_t)s1 * 32 + lane]);
        float2 f2 = __half22float2(H2[(size_t)s2 * 32 + lane]);
        float2 f3 = __half22float2(H2[(size_t)s3 * 32 + lane]);
        ax += (f0.x + f1.x) + (f2.x + f3.x);
        ay += (f0.y + f1.y) + (f2.y + f3.y);
    }
    for (; e < o1; ++e) {
        float2 f0 = __half22float2(H2[(size_t)csr[e] * 32 + lane]);
        ax += f0.x; ay += f0.y;
    }
    float2 fs = __half22float2(H2[(size_t)node * 32 + lane]);
    float di = dinv[node];
    float2 bv = ((const float2*)bias)[lane];
    float vx = di * (ax + fs.x) + bv.x;
    float vy = di * (ay + fs.y) + bv.y;
    if (RELU) { vx = vx > 0.f ? vx : 0.2f * vx; vy = vy > 0.f ? vy : 0.2f * vy; }
    if (OUT16)
        ((__half2*)Y)[(size_t)node * 32 + lane] = __floats2half2_rn(vx, vy);
    else
        ((float2*)Y)[(size_t)node * 32 + lane] = make_float2(vx, vy);
}

__global__ __launch_bounds__(256) void k_agg64y(const __half* Hh, const int* offs,
                                                const int* csr, const float* dinv,
                                                const float* bias, __half* Y, int N) {
    agg64_body<true, true>(Hh, offs, csr, dinv, bias, Y, N);
}
__global__ __launch_bounds__(256) void k_agg64out(const __half* Hh, const int* offs,
                                                  const int* csr, const float* dinv,
                                                  const float* bias, float* Y, int N) {
    agg64_body<false, false>(Hh, offs, csr, dinv, bias, Y, N);
}

extern "C" void kernel_launch(void* const* d_in, const int* in_sizes, int n_in,
                              void* d_out, int out_size, void* d_ws, size_t ws_size,
                              hipStream_t stream) {
    const float* x  = (const float*)d_in[0];
    const int*   ei = (const int*)d_in[1];
    const float* W1 = (const float*)d_in[2];
    const float* b1 = (const float*)d_in[3];
    const float* W2 = (const float*)d_in[4];
    const float* b2 = (const float*)d_in[5];
    const float* W3 = (const float*)d_in[6];
    const float* b3 = (const float*)d_in[7];

    const int N = in_sizes[0] / 512;
    const int E = in_sizes[1] / 2;
    const int nb = (N + 255) / 256;

    char* w = (char*)d_ws;
    auto take = [&](size_t bytes) -> char* {
        char* p = w;
        w += alignup(bytes, 256);
        return p;
    };
    int*    flag  = (int*)take(256);
    int*    deg   = (int*)take((size_t)N * 4);     // deg -> inclusive sctr
    int*    offs  = (int*)take((size_t)(N + 1) * 4);
    int*    bsums = (int*)take((size_t)nb * 4);
    int*    csr   = (int*)take((size_t)E * 4);
    float*  dinv  = (float*)take((size_t)N * 4);
    __half* bufA  = (__half*)take((size_t)N * 128 * 2);   // H' fp16
    __half* bufY  = (__half*)take((size_t)N * 128 * 2);   // y fp16
    u16*    w1h   = (u16*)take((size_t)512 * 128 * 2);
    u16*    w1l   = (u16*)take((size_t)512 * 128 * 2);
    u16*    w2h   = (u16*)take((size_t)128 * 64 * 2);
    u16*    w2l   = (u16*)take((size_t)128 * 64 * 2);
    u16*    w3h   = (u16*)take((size_t)64 * 64 * 2);
    u16*    w3l   = (u16*)take((size_t)64 * 64 * 2);

    const int TB = 256;
    // preprocessing (5 launches)
    k_init_split<<<nb + 38, TB, 0, stream>>>(ei, flag, deg, N, nb,
                                             W1, w1h, w1l, W2, w2h, w2l,
                                             W3, w3h, w3l);
    k_deg<<<(E + TB - 1) / TB, TB, 0, stream>>>(ei, E, flag, deg);
    k_scan1<<<nb, 256, 0, stream>>>(deg, offs, bsums, dinv, N);
    k_scan23<<<nb, 256, 0, stream>>>(offs, bsums, deg, nb, N, E);
    k_fill<<<(E + TB - 1) / TB, TB, 0, stream>>>(ei, E, flag, deg, csr);

    const int rowtiles = (N + 63) / 64;
    // layer 1
    k_gemm_bf16<<<rowtiles, 128, 0, stream>>>(x, w1h, w1l, dinv, bufA, N);
    k_agg128<<<(N + 3) / 4, 256, 0, stream>>>(bufA, offs, csr, dinv, b1, bufY, N);
    // layer 2
    k_gemm2<<<rowtiles, 128, 0, stream>>>(bufY, w2h, w2l, dinv, bufA, N);
    k_agg64y<<<(N + 7) / 8, 256, 0, stream>>>(bufA, offs, csr, dinv, b2, bufY, N);
    // layer 3
    k_gemm3<<<rowtiles, 128, 0, stream>>>(bufY, w3h, w3l, dinv, bufA, N);
    k_agg64out<<<(N + 7) / 8, 256, 0, stream>>>(bufA, offs, csr, dinv, b3,
                                                (float*)d_out, N);
}

// Round 20
// 182.266 us; speedup vs baseline: 1.3012x; 1.3012x over previous
//
#include <hip/hip_runtime.h>
#include <hip/hip_fp16.h>

// ---------------------------------------------------------------------------
// GCN 3-layer forward on MI355X.  (r20: rank-trick fill + fill||gemm1 fusion)
// init+splitW -> deg(+rank out) -> scan1(+dinv) -> scan23 ->
//   [k_gemm1_fill: gemm1 blocks || atomic-free fill blocks] -> k_agg128 ->
//   k_gemm2 -> k_agg64y -> k_gemm3 -> k_agg64out          (9 launches)
// r19 post-mortem: nt-store WORSE (59MB HBM partial-line writes); k_fill is
// atomic-round-trip bound (VALU 0.4%). Fixes: (1) rank = return value of
// k_deg's existing atomicAdd (free) -> fill has NO atomic; (2) fill blocks
// fused into gemm1 kernel -> latency hides under gemm compute.
// ---------------------------------------------------------------------------

typedef __attribute__((ext_vector_type(8))) short bf16x8;
typedef __attribute__((ext_vector_type(8))) _Float16 f16x8;
typedef __attribute__((ext_vector_type(4))) float f32x4;
typedef unsigned short u16;
typedef unsigned int u32;

static inline size_t alignup(size_t v, size_t a) { return (v + a - 1) & ~(a - 1); }

__device__ __forceinline__ u32 pack_hi16(u32 b0, u32 b1) {
    return __builtin_amdgcn_perm(b1, b0, 0x07060302u);   // top16(b0)|top16(b1)
}

// --- W1 split: fragment-ordered bf16 hi/lo -----------------------------------
__device__ __forceinline__ void splitW_bf16(const float* __restrict__ W,
                                            u16* __restrict__ Wh,
                                            u16* __restrict__ Wl, int s, int F) {
    int c = s % F;
    int kb = (s / F) * 8;
    union { u32 u[4]; bf16x8 v; } hi, lo;
#pragma unroll
    for (int p = 0; p < 4; p++) {
        float x0 = W[(size_t)(kb + 2 * p) * F + c];
        float x1 = W[(size_t)(kb + 2 * p + 1) * F + c];
        u32 b0 = __float_as_uint(x0), b1 = __float_as_uint(x1);
        float l0 = x0 - __uint_as_float(b0 & 0xFFFF0000u);
        float l1 = x1 - __uint_as_float(b1 & 0xFFFF0000u);
        hi.u[p] = pack_hi16(b0, b1);
        lo.u[p] = pack_hi16(__float_as_uint(l0), __float_as_uint(l1));
    }
    *(bf16x8*)(Wh + (size_t)s * 8) = hi.v;
    *(bf16x8*)(Wl + (size_t)s * 8) = lo.v;
}

// --- W2/W3 split: fragment-ordered fp16 hi/lo (22-bit effective) -------------
__device__ __forceinline__ void splitW_f16(const float* __restrict__ W,
                                           u16* __restrict__ Wh,
                                           u16* __restrict__ Wl, int s, int F) {
    int c = s % F;
    int kb = (s / F) * 8;
    union { u16 u[8]; bf16x8 v; } hi, lo;
#pragma unroll
    for (int p = 0; p < 8; p++) {
        float xv = W[(size_t)(kb + p) * F + c];
        __half h = __float2half(xv);
        __half l = __float2half(xv - __half2float(h));
        hi.u[p] = __half_as_ushort(h);
        lo.u[p] = __half_as_ushort(l);
    }
    *(bf16x8*)(Wh + (size_t)s * 8) = hi.v;
    *(bf16x8*)(Wl + (size_t)s * 8) = lo.v;
}

// --- init (zero deg + detect layout) fused with W splits ---------------------
__global__ void k_init_split(const int* __restrict__ ei, int* __restrict__ flag,
                             int* __restrict__ deg, int N, int nb,
                             const float* __restrict__ W1, u16* w1h, u16* w1l,
                             const float* __restrict__ W2, u16* w2h, u16* w2l,
                             const float* __restrict__ W3, u16* w3h, u16* w3l) {
    int b = blockIdx.x;
    if (b < nb) {
        int i = b * 256 + threadIdx.x;
        if (i < N) deg[i] = 0;
        if (b == 0 && threadIdx.x < 64) {
            int v = ei[2 * threadIdx.x + 1];          // high word if int64
            unsigned long long m = __ballot(v != 0);
            if (threadIdx.x == 0) *flag = (m == 0ull) ? 1 : 0;
        }
        return;
    }
    int s = (b - nb) * 256 + threadIdx.x;
    if (s < 8192) splitW_bf16(W1, w1h, w1l, s, 128);              // 512x128/8
    else if (s < 9216) splitW_f16(W2, w2h, w2l, s - 8192, 64);    // 128x64/8
    else if (s < 9728) splitW_f16(W3, w3h, w3l, s - 9216, 64);    // 64x64/8
}

// --- degree count; the atomic's RETURN VALUE is the edge's rank (free) -------
__global__ void k_deg(const int* __restrict__ ei, int E,
                      const int* __restrict__ flag, int* __restrict__ deg,
                      int* __restrict__ rank) {
    int i = blockIdx.x * blockDim.x + threadIdx.x;
    if (i >= E) return;
    int is64 = *flag;
    int d = is64 ? ei[2 * (E + i)] : ei[E + i];
    rank[i] = atomicAdd(&deg[d], 1);
}

__global__ void k_scan1(const int* __restrict__ deg, int* __restrict__ offs,
                        int* __restrict__ bsums, float* __restrict__ dinv, int N) {
    __shared__ int s[256];
    int i = blockIdx.x * 256 + threadIdx.x;
    int v = (i < N) ? deg[i] : 0;
    if (i < N) dinv[i] = rsqrtf((float)v + 1.0f);
    s[threadIdx.x] = v;
    __syncthreads();
    for (int off = 1; off < 256; off <<= 1) {
        int t = (threadIdx.x >= off) ? s[threadIdx.x - off] : 0;
        __syncthreads();
        s[threadIdx.x] += t;
        __syncthreads();
    }
    if (i < N) offs[i] = s[threadIdx.x] - v;   // exclusive
    if (threadIdx.x == 255) bsums[blockIdx.x] = s[255];
}

__global__ void k_scan23(int* __restrict__ offs, const int* __restrict__ bsums,
                         int nb, int N, int E) {
    __shared__ int s[256];
    int tid = threadIdx.x;
    s[tid] = (tid < nb) ? bsums[tid] : 0;
    __syncthreads();
    for (int off = 1; off < 256; off <<= 1) {
        int t = (tid >= off) ? s[tid - off] : 0;
        __syncthreads();
        s[tid] += t;                 // inclusive scan
        __syncthreads();
    }
    int boff = (blockIdx.x > 0) ? s[blockIdx.x - 1] : 0;
    int i = blockIdx.x * 256 + tid;
    if (i < N) offs[i] += boff;
    if (i == 0) offs[N] = E;
}

// --- FUSED: gemm1 blocks [0,rowtiles) || atomic-free fill blocks -------------
// gemm1: H'[N,128] = dinv * (X[N,512] @ W1), bf16x3 split, fp16 out.
//   128 thr = 2 waves (col halves), wave tile 64x64 (MF=4, NF=4), A K-tile
//   [64][32] f32 dbuf LDS via global_load_lds (src chunk-swizzle c^=(row&7)).
// fill: csr[offs[d] + rank[i]] = src (no atomic; offs is L2-replicated).
__global__ __launch_bounds__(128) void k_gemm1_fill(
        const float* __restrict__ X,
        const u16* __restrict__ Wh, const u16* __restrict__ Wl,
        const float* __restrict__ dinv, __half* __restrict__ Hh, int N,
        int rowtiles,
        const int* __restrict__ ei, int E, const int* __restrict__ flag,
        const int* __restrict__ offs, const int* __restrict__ rank,
        int* __restrict__ csr) {
    constexpr int K = 512, F = 128, MF = 4, NF = 4, NT = K / 32;
    __shared__ float4 smemA[2][512];   // 2 x 8 KB (gemm path only)

    if ((int)blockIdx.x >= rowtiles) {
        // ---- fill path: latency-bound, hides under gemm compute ----
        int i = ((int)blockIdx.x - rowtiles) * 128 + threadIdx.x;
        if (i < E) {
            int is64 = *flag;
            int s = is64 ? ei[2 * i] : ei[i];
            int d = is64 ? ei[2 * (E + i)] : ei[E + i];
            csr[offs[d] + rank[i]] = s;
        }
        return;
    }

    // ---- gemm1 path (r14/r18 structure, unchanged) ----
    const int tid = threadIdx.x;
    const int lane = tid & 63;
    const int w = tid >> 6;
    const int colbase = w * (NF * 16);
    const int lg = lane >> 4, li = lane & 15;
    const int row0 = blockIdx.x * 64;

    auto stage = [&](int b, int t) {
#pragma unroll
        for (int j = 0; j < 4; j++) {
            int c_lin = j * 128 + tid;
            int row = c_lin >> 3, c = c_lin & 7;
            int rg = row0 + row;
            if (rg >= N) rg = N - 1;
            int cs = c ^ (row & 7);
            const float* g = X + (size_t)rg * K + t * 32 + cs * 4;
            char* l = (char*)&smemA[b][0] + j * 2048 + w * 1024;
            __builtin_amdgcn_global_load_lds(
                (const __attribute__((address_space(1))) void*)g,
                (__attribute__((address_space(3))) void*)l, 16, 0, 0);
        }
    };

    f32x4 acc[MF][NF];
#pragma unroll
    for (int m = 0; m < MF; m++)
#pragma unroll
        for (int n = 0; n < NF; n++) acc[m][n] = (f32x4){0.f, 0.f, 0.f, 0.f};

    stage(0, 0);
    __syncthreads();

    for (int t = 0; t < NT; t++) {
        const int b = t & 1;
        bf16x8 bh[NF], bl[NF];
        size_t slot0 = (size_t)(t * 4 + lg) * F + colbase + li;
#pragma unroll
        for (int n = 0; n < NF; n++) {
            bh[n] = *(const bf16x8*)(Wh + (slot0 + n * 16) * 8);
            bl[n] = *(const bf16x8*)(Wl + (slot0 + n * 16) * 8);
        }
        __builtin_amdgcn_sched_barrier(0);
        if (t + 1 < NT) stage(b ^ 1, t + 1);
        const float4* lt = &smemA[b][0];
        bf16x8 ah[MF], al[MF];
#pragma unroll
        for (int m = 0; m < MF; m++) {
            int row = m * 16 + li;
            int base = row * 8, sw = row & 7;
            float4 c0 = lt[base + ((2 * lg) ^ sw)];
            float4 c1 = lt[base + ((2 * lg + 1) ^ sw)];
            float xv[8] = {c0.x, c0.y, c0.z, c0.w, c1.x, c1.y, c1.z, c1.w};
            union { u32 u[4]; bf16x8 v; } hi, lo;
#pragma unroll
            for (int q = 0; q < 4; q++) {
                u32 b0 = __float_as_uint(xv[2 * q]);
                u32 b1 = __float_as_uint(xv[2 * q + 1]);
                float l0 = xv[2 * q]     - __uint_as_float(b0 & 0xFFFF0000u);
                float l1 = xv[2 * q + 1] - __uint_as_float(b1 & 0xFFFF0000u);
                hi.u[q] = pack_hi16(b0, b1);
                lo.u[q] = pack_hi16(__float_as_uint(l0), __float_as_uint(l1));
            }
            ah[m] = hi.v;
            al[m] = lo.v;
        }
#pragma unroll
        for (int m = 0; m < MF; m++)
#pragma unroll
            for (int n = 0; n < NF; n++) {
                acc[m][n] = __builtin_amdgcn_mfma_f32_16x16x32_bf16(ah[m], bh[n], acc[m][n], 0, 0, 0);
                acc[m][n] = __builtin_amdgcn_mfma_f32_16x16x32_bf16(ah[m], bl[n], acc[m][n], 0, 0, 0);
                acc[m][n] = __builtin_amdgcn_mfma_f32_16x16x32_bf16(al[m], bh[n], acc[m][n], 0, 0, 0);
            }
        __syncthreads();
    }

#pragma unroll
    for (int m = 0; m < MF; m++) {
        int rb = row0 + m * 16 + lg * 4;
#pragma unroll
        for (int r = 0; r < 4; r++) {
            int gr = rb + r;
            if (gr >= N) continue;
            float di = dinv[gr];
#pragma unroll
            for (int n = 0; n < NF; n++) {
                int col = colbase + n * 16 + li;
                Hh[(size_t)gr * F + col] = __float2half(acc[m][n][r] * di);
            }
        }
    }
}

// --- L2/L3 GEMM body: H'[N,64] = dinv * (Y[N,K] @ W), Y fp16 EXACT -----------
template <int K>
__device__ __forceinline__ void gemm_f16_body(
        const __half* __restrict__ Y,
        const u16* __restrict__ Wh, const u16* __restrict__ Wl,
        const float* __restrict__ dinv, __half* __restrict__ Hh, int N) {
    constexpr int F = 64, MF = 4, NF = 2, NT = K / 32;
    __shared__ float4 smemA[2][256];   // 2 x 4 KB

    const int tid = threadIdx.x;
    const int lane = tid & 63;
    const int w = tid >> 6;
    const int colbase = w * (NF * 16);
    const int lg = lane >> 4, li = lane & 15;
    const int row0 = blockIdx.x * 64;

    auto stage = [&](int b, int t) {
#pragma unroll
        for (int j = 0; j < 2; j++) {
            int c_lin = j * 128 + tid;          // 0..255
            int row = c_lin >> 2, c = c_lin & 3;
            int rg = row0 + row;
            if (rg >= N) rg = N - 1;
            int cs = c ^ (row & 3);
            const __half* g = Y + (size_t)rg * K + t * 32 + cs * 8;  // 16 B
            char* l = (char*)&smemA[b][0] + j * 2048 + w * 1024;
            __builtin_amdgcn_global_load_lds(
                (const __attribute__((address_space(1))) void*)g,
                (__attribute__((address_space(3))) void*)l, 16, 0, 0);
        }
    };

    f32x4 acc[MF][NF];
#pragma unroll
    for (int m = 0; m < MF; m++)
#pragma unroll
        for (int n = 0; n < NF; n++) acc[m][n] = (f32x4){0.f, 0.f, 0.f, 0.f};

    stage(0, 0);
    __syncthreads();

    for (int t = 0; t < NT; t++) {
        const int b = t & 1;
        f16x8 bh[NF], bl[NF];
        size_t slot0 = (size_t)(t * 4 + lg) * F + colbase + li;
#pragma unroll
        for (int n = 0; n < NF; n++) {
            bh[n] = *(const f16x8*)(Wh + (slot0 + n * 16) * 8);
            bl[n] = *(const f16x8*)(Wl + (slot0 + n * 16) * 8);
        }
        __builtin_amdgcn_sched_barrier(0);
        if (t + 1 < NT) stage(b ^ 1, t + 1);
        const float4* lt = &smemA[b][0];
        f16x8 a[MF];
#pragma unroll
        for (int m = 0; m < MF; m++) {
            int row = m * 16 + li;
            union { float4 f; f16x8 h; } u;
            u.f = lt[row * 4 + (lg ^ (row & 3))];
            a[m] = u.h;
        }
#pragma unroll
        for (int m = 0; m < MF; m++)
#pragma unroll
            for (int n = 0; n < NF; n++) {
                acc[m][n] = __builtin_amdgcn_mfma_f32_16x16x32_f16(a[m], bh[n], acc[m][n], 0, 0, 0);
                acc[m][n] = __builtin_amdgcn_mfma_f32_16x16x32_f16(a[m], bl[n], acc[m][n], 0, 0, 0);
            }
        __syncthreads();
    }

#pragma unroll
    for (int m = 0; m < MF; m++) {
        int rb = row0 + m * 16 + lg * 4;
#pragma unroll
        for (int r = 0; r < 4; r++) {
            int gr = rb + r;
            if (gr >= N) continue;
            float di = dinv[gr];
#pragma unroll
            for (int n = 0; n < NF; n++) {
                int col = colbase + n * 16 + li;
                Hh[(size_t)gr * F + col] = __float2half(acc[m][n][r] * di);
            }
        }
    }
}

__global__ __launch_bounds__(128) void k_gemm2(
        const __half* __restrict__ Y, const u16* __restrict__ Wh,
        const u16* __restrict__ Wl, const float* __restrict__ dinv,
        __half* __restrict__ Hh, int N) {
    gemm_f16_body<128>(Y, Wh, Wl, dinv, Hh, N);
}
__global__ __launch_bounds__(128) void k_gemm3(
        const __half* __restrict__ Y, const u16* __restrict__ Wh,
        const u16* __restrict__ Wl, const float* __restrict__ dinv,
        __half* __restrict__ Hh, int N) {
    gemm_f16_body<64>(Y, Wh, Wl, dinv, Hh, N);
}

// --- agg, F=128, fp16 H' in, fp16 y out (leaky-relu); 8-edge unroll -----------
__global__ __launch_bounds__(256) void k_agg128(const __half* __restrict__ Hh,
                                                const int* __restrict__ offs,
                                                const int* __restrict__ csr,
                                                const float* __restrict__ dinv,
                                                const float* __restrict__ bias,
                                                __half* __restrict__ Y, int N) {
    int node = blockIdx.x * 4 + (threadIdx.x >> 6);
    int lane = threadIdx.x & 63;
    if (node >= N) return;
    const __half2* H2 = (const __half2*)Hh;   // row = 64 half2
    float ax = 0.f, ay = 0.f;
    int o0 = offs[node], o1 = offs[node + 1];
    int e = o0;
    for (; e + 8 <= o1; e += 8) {
        int s[8];
#pragma unroll
        for (int q = 0; q < 8; q++) s[q] = csr[e + q];
        float2 f[8];
#pragma unroll
        for (int q = 0; q < 8; q++)
            f[q] = __half22float2(H2[(size_t)s[q] * 64 + lane]);
#pragma unroll
        for (int q = 0; q < 8; q++) { ax += f[q].x; ay += f[q].y; }
    }
    for (; e + 4 <= o1; e += 4) {
        int s0 = csr[e], s1 = csr[e + 1], s2 = csr[e + 2], s3 = csr[e + 3];
        float2 f0 = __half22float2(H2[(size_t)s0 * 64 + lane]);
        float2 f1 = __half22float2(H2[(size_t)s1 * 64 + lane]);
        float2 f2 = __half22float2(H2[(size_t)s2 * 64 + lane]);
        float2 f3 = __half22float2(H2[(size_t)s3 * 64 + lane]);
        ax += (f0.x + f1.x) + (f2.x + f3.x);
        ay += (f0.y + f1.y) + (f2.y + f3.y);
    }
    for (; e < o1; ++e) {
        float2 f0 = __half22float2(H2[(size_t)csr[e] * 64 + lane]);
        ax += f0.x; ay += f0.y;
    }
    float2 fs = __half22float2(H2[(size_t)node * 64 + lane]);
    float di = dinv[node];
    float2 bv = ((const float2*)bias)[lane];
    float vx = di * (ax + fs.x) + bv.x;
    float vy = di * (ay + fs.y) + bv.y;
    vx = vx > 0.f ? vx : 0.2f * vx;
    vy = vy > 0.f ? vy : 0.2f * vy;
    ((__half2*)Y)[(size_t)node * 64 + lane] = __floats2half2_rn(vx, vy);
}

// --- agg, F=64, fp16 H' in — shared body, fp16-y or f32-out; 8-edge unroll ----
template <bool RELU, bool OUT16>
__device__ __forceinline__ void agg64_body(const __half* __restrict__ Hh,
                                           const int* __restrict__ offs,
                                           const int* __restrict__ csr,
                                           const float* __restrict__ dinv,
                                           const float* __restrict__ bias,
                                           void* __restrict__ Y, int N) {
    int node = blockIdx.x * 8 + (threadIdx.x >> 5);
    int lane = threadIdx.x & 31;
    if (node >= N) return;
    const __half2* H2 = (const __half2*)Hh;   // row = 32 half2
    float ax = 0.f, ay = 0.f;
    int o0 = offs[node], o1 = offs[node + 1];
    int e = o0;
    for (; e + 8 <= o1; e += 8) {
        int s[8];
#pragma unroll
        for (int q = 0; q < 8; q++) s[q] = csr[e + q];
        float2 f[8];
#pragma unroll
        for (int q = 0; q < 8; q++)
            f[q] = __half22float2(H2[(size_t)s[q] * 32 + lane]);
#pragma unroll
        for (int q = 0; q < 8; q++) { ax += f[q].x; ay += f[q].y; }
    }
    for (; e + 4 <= o1; e += 4) {
        int s0 = csr[e], s1 = csr[e + 1], s2 = csr[e + 2], s3 = csr[e + 3];
        float2 f0 = __half22float2(H2[(size_t)s0 * 32 + lane]);
        float2 f1 = __half22float2(H2[(size_t)s1 * 32 + lane]);
        float2 f2 = __half22float2(H2[(size_t)s2 * 32 + lane]);
        float2 f3 = __half22float2(H2[(size_t)s3 * 32 + lane]);
        ax += (f0.x + f1.x) + (f2.x + f3.x);
        ay += (f0.y + f1.y) + (f2.y + f3.y);
    }
    for (; e < o1; ++e) {
        float2 f0 = __half22float2(H2[(size_t)csr[e] * 32 + lane]);
        ax += f0.x; ay += f0.y;
    }
    float2 fs = __half22float2(H2[(size_t)node * 32 + lane]);
    float di = dinv[node];
    float2 bv = ((const float2*)bias)[lane];
    float vx = di * (ax + fs.x) + bv.x;
    float vy = di * (ay + fs.y) + bv.y;
    if (RELU) { vx = vx > 0.f ? vx : 0.2f * vx; vy = vy > 0.f ? vy : 0.2f * vy; }
    if (OUT16)
        ((__half2*)Y)[(size_t)node * 32 + lane] = __floats2half2_rn(vx, vy);
    else
        ((float2*)Y)[(size_t)node * 32 + lane] = make_float2(vx, vy);
}

__global__ __launch_bounds__(256) void k_agg64y(const __half* Hh, const int* offs,
                                                const int* csr, const float* dinv,
                                                const float* bias, __half* Y, int N) {
    agg64_body<true, true>(Hh, offs, csr, dinv, bias, Y, N);
}
__global__ __launch_bounds__(256) void k_agg64out(const __half* Hh, const int* offs,
                                                  const int* csr, const float* dinv,
                                                  const float* bias, float* Y, int N) {
    agg64_body<false, false>(Hh, offs, csr, dinv, bias, Y, N);
}

extern "C" void kernel_launch(void* const* d_in, const int* in_sizes, int n_in,
                              void* d_out, int out_size, void* d_ws, size_t ws_size,
                              hipStream_t stream) {
    const float* x  = (const float*)d_in[0];
    const int*   ei = (const int*)d_in[1];
    const float* W1 = (const float*)d_in[2];
    const float* b1 = (const float*)d_in[3];
    const float* W2 = (const float*)d_in[4];
    const float* b2 = (const float*)d_in[5];
    const float* W3 = (const float*)d_in[6];
    const float* b3 = (const float*)d_in[7];

    const int N = in_sizes[0] / 512;
    const int E = in_sizes[1] / 2;
    const int nb = (N + 255) / 256;

    char* w = (char*)d_ws;
    auto take = [&](size_t bytes) -> char* {
        char* p = w;
        w += alignup(bytes, 256);
        return p;
    };
    int*    flag  = (int*)take(256);
    int*    deg   = (int*)take((size_t)N * 4);
    int*    offs  = (int*)take((size_t)(N + 1) * 4);
    int*    bsums = (int*)take((size_t)nb * 4);
    int*    csr   = (int*)take((size_t)E * 4);
    int*    rank  = (int*)take((size_t)E * 4);
    float*  dinv  = (float*)take((size_t)N * 4);
    __half* bufA  = (__half*)take((size_t)N * 128 * 2);   // H' fp16
    __half* bufY  = (__half*)take((size_t)N * 128 * 2);   // y fp16
    u16*    w1h   = (u16*)take((size_t)512 * 128 * 2);
    u16*    w1l   = (u16*)take((size_t)512 * 128 * 2);
    u16*    w2h   = (u16*)take((size_t)128 * 64 * 2);
    u16*    w2l   = (u16*)take((size_t)128 * 64 * 2);
    u16*    w3h   = (u16*)take((size_t)64 * 64 * 2);
    u16*    w3l   = (u16*)take((size_t)64 * 64 * 2);

    const int TB = 256;
    // preprocessing (4 launches)
    k_init_split<<<nb + 38, TB, 0, stream>>>(ei, flag, deg, N, nb,
                                             W1, w1h, w1l, W2, w2h, w2l,
                                             W3, w3h, w3l);
    k_deg<<<(E + TB - 1) / TB, TB, 0, stream>>>(ei, E, flag, deg, rank);
    k_scan1<<<nb, 256, 0, stream>>>(deg, offs, bsums, dinv, N);
    k_scan23<<<nb, 256, 0, stream>>>(offs, bsums, nb, N, E);

    const int rowtiles = (N + 63) / 64;
    const int fillblocks = (E + 127) / 128;
    // layer 1 GEMM fused with atomic-free CSR fill (independent work)
    k_gemm1_fill<<<rowtiles + fillblocks, 128, 0, stream>>>(
        x, w1h, w1l, dinv, bufA, N, rowtiles, ei, E, flag, offs, rank, csr);
    k_agg128<<<(N + 3) / 4, 256, 0, stream>>>(bufA, offs, csr, dinv, b1, bufY, N);
    // layer 2
    k_gemm2<<<rowtiles, 128, 0, stream>>>(bufY, w2h, w2l, dinv, bufA, N);
    k_agg64y<<<(N + 7) / 8, 256, 0, stream>>>(bufA, offs, csr, dinv, b2, bufY, N);
    // layer 3
    k_gemm3<<<rowtiles, 128, 0, stream>>>(bufY, w3h, w3l, dinv, bufA, N);
    k_agg64out<<<(N + 7) / 8, 256, 0, stream>>>(bufA, offs, csr, dinv, b3,
                                                (float*)d_out, N);
}

// Round 21
// 182.042 us; speedup vs baseline: 1.3028x; 1.0012x over previous
//
#include <hip/hip_runtime.h>
#include <hip/hip_fp16.h>

// ---------------------------------------------------------------------------
// GCN 3-layer forward on MI355X.  (r21: deg fused into init; memsetAsync zero)
// memset(deg) -> [init: splitW+flag || deg(+rank), per-wave layout detect]
//   -> scan1(+dinv) -> scan23 -> [gemm1 || atomic-free fill] -> agg128
//   -> gemm2 -> agg64y -> gemm3 -> agg64out            (8 launches + memset)
// r20 post-mortem: fill||gemm1 fusion = -55us (fusion is the ONLY overlap
// tool on one stream). Remaining serial pre-chain init(8)+deg(15) -> fused:
// concurrent blocks => ~max(15,3). deg blocks self-detect int64 layout via
// per-wave ballot (can't read flag written by block 0 of same kernel).
// ---------------------------------------------------------------------------

typedef __attribute__((ext_vector_type(8))) short bf16x8;
typedef __attribute__((ext_vector_type(8))) _Float16 f16x8;
typedef __attribute__((ext_vector_type(4))) float f32x4;
typedef unsigned short u16;
typedef unsigned int u32;

static inline size_t alignup(size_t v, size_t a) { return (v + a - 1) & ~(a - 1); }

__device__ __forceinline__ u32 pack_hi16(u32 b0, u32 b1) {
    return __builtin_amdgcn_perm(b1, b0, 0x07060302u);   // top16(b0)|top16(b1)
}

// --- W1 split: fragment-ordered bf16 hi/lo -----------------------------------
__device__ __forceinline__ void splitW_bf16(const float* __restrict__ W,
                                            u16* __restrict__ Wh,
                                            u16* __restrict__ Wl, int s, int F) {
    int c = s % F;
    int kb = (s / F) * 8;
    union { u32 u[4]; bf16x8 v; } hi, lo;
#pragma unroll
    for (int p = 0; p < 4; p++) {
        float x0 = W[(size_t)(kb + 2 * p) * F + c];
        float x1 = W[(size_t)(kb + 2 * p + 1) * F + c];
        u32 b0 = __float_as_uint(x0), b1 = __float_as_uint(x1);
        float l0 = x0 - __uint_as_float(b0 & 0xFFFF0000u);
        float l1 = x1 - __uint_as_float(b1 & 0xFFFF0000u);
        hi.u[p] = pack_hi16(b0, b1);
        lo.u[p] = pack_hi16(__float_as_uint(l0), __float_as_uint(l1));
    }
    *(bf16x8*)(Wh + (size_t)s * 8) = hi.v;
    *(bf16x8*)(Wl + (size_t)s * 8) = lo.v;
}

// --- W2/W3 split: fragment-ordered fp16 hi/lo (22-bit effective) -------------
__device__ __forceinline__ void splitW_f16(const float* __restrict__ W,
                                           u16* __restrict__ Wh,
                                           u16* __restrict__ Wl, int s, int F) {
    int c = s % F;
    int kb = (s / F) * 8;
    union { u16 u[8]; bf16x8 v; } hi, lo;
#pragma unroll
    for (int p = 0; p < 8; p++) {
        float xv = W[(size_t)(kb + p) * F + c];
        __half h = __float2half(xv);
        __half l = __float2half(xv - __half2float(h));
        hi.u[p] = __half_as_ushort(h);
        lo.u[p] = __half_as_ushort(l);
    }
    *(bf16x8*)(Wh + (size_t)s * 8) = hi.v;
    *(bf16x8*)(Wl + (size_t)s * 8) = lo.v;
}

// --- FUSED init: splitW+flag blocks [0,38) || deg+rank blocks [38,...) -------
// deg requires deg[] pre-zeroed (hipMemsetAsync). Each deg WAVE detects the
// edge layout itself (ballot over the first 64 hi-words, L2-hot) since flag
// (written by block 0 here) cannot be read race-free within this kernel.
__global__ void k_init_deg(const int* __restrict__ ei, int E,
                           int* __restrict__ flag,
                           int* __restrict__ deg, int* __restrict__ rank,
                           const float* __restrict__ W1, u16* w1h, u16* w1l,
                           const float* __restrict__ W2, u16* w2h, u16* w2l,
                           const float* __restrict__ W3, u16* w3h, u16* w3l) {
    constexpr int SPLITB = 38;                 // 9728/256
    int b = blockIdx.x;
    if (b < SPLITB) {
        if (b == 0 && threadIdx.x < 64) {      // flag for LATER kernels
            int v = ei[2 * threadIdx.x + 1];
            unsigned long long m = __ballot(v != 0);
            if (threadIdx.x == 0) *flag = (m == 0ull) ? 1 : 0;
        }
        int s = b * 256 + threadIdx.x;
        if (s < 8192) splitW_bf16(W1, w1h, w1l, s, 128);           // 512x128/8
        else if (s < 9216) splitW_f16(W2, w2h, w2l, s - 8192, 64); // 128x64/8
        else if (s < 9728) splitW_f16(W3, w3h, w3l, s - 9216, 64); // 64x64/8
        return;
    }
    // per-wave layout detect (identical result in every wave, race-free)
    int v = ei[2 * (threadIdx.x & 63) + 1];
    unsigned long long m = __ballot(v != 0);
    int is64 = (m == 0ull) ? 1 : 0;
    int i = (b - SPLITB) * 256 + threadIdx.x;
    if (i >= E) return;
    int d = is64 ? ei[2 * (E + i)] : ei[E + i];
    rank[i] = atomicAdd(&deg[d], 1);           // return value = edge rank
}

__global__ void k_scan1(const int* __restrict__ deg, int* __restrict__ offs,
                        int* __restrict__ bsums, float* __restrict__ dinv, int N) {
    __shared__ int s[256];
    int i = blockIdx.x * 256 + threadIdx.x;
    int v = (i < N) ? deg[i] : 0;
    if (i < N) dinv[i] = rsqrtf((float)v + 1.0f);
    s[threadIdx.x] = v;
    __syncthreads();
    for (int off = 1; off < 256; off <<= 1) {
        int t = (threadIdx.x >= off) ? s[threadIdx.x - off] : 0;
        __syncthreads();
        s[threadIdx.x] += t;
        __syncthreads();
    }
    if (i < N) offs[i] = s[threadIdx.x] - v;   // exclusive
    if (threadIdx.x == 255) bsums[blockIdx.x] = s[255];
}

__global__ void k_scan23(int* __restrict__ offs, const int* __restrict__ bsums,
                         int nb, int N, int E) {
    __shared__ int s[256];
    int tid = threadIdx.x;
    s[tid] = (tid < nb) ? bsums[tid] : 0;
    __syncthreads();
    for (int off = 1; off < 256; off <<= 1) {
        int t = (tid >= off) ? s[tid - off] : 0;
        __syncthreads();
        s[tid] += t;                 // inclusive scan
        __syncthreads();
    }
    int boff = (blockIdx.x > 0) ? s[blockIdx.x - 1] : 0;
    int i = blockIdx.x * 256 + tid;
    if (i < N) offs[i] += boff;
    if (i == 0) offs[N] = E;
}

// --- FUSED: gemm1 blocks [0,rowtiles) || atomic-free fill blocks -------------
__global__ __launch_bounds__(128) void k_gemm1_fill(
        const float* __restrict__ X,
        const u16* __restrict__ Wh, const u16* __restrict__ Wl,
        const float* __restrict__ dinv, __half* __restrict__ Hh, int N,
        int rowtiles,
        const int* __restrict__ ei, int E, const int* __restrict__ flag,
        const int* __restrict__ offs, const int* __restrict__ rank,
        int* __restrict__ csr) {
    constexpr int K = 512, F = 128, MF = 4, NF = 4, NT = K / 32;
    __shared__ float4 smemA[2][512];   // 2 x 8 KB (gemm path only)

    if ((int)blockIdx.x >= rowtiles) {
        // ---- fill path: latency-bound, hides under gemm compute ----
        int i = ((int)blockIdx.x - rowtiles) * 128 + threadIdx.x;
        if (i < E) {
            int is64 = *flag;
            int s = is64 ? ei[2 * i] : ei[i];
            int d = is64 ? ei[2 * (E + i)] : ei[E + i];
            csr[offs[d] + rank[i]] = s;
        }
        return;
    }

    // ---- gemm1 path (r14/r18 structure) ----
    const int tid = threadIdx.x;
    const int lane = tid & 63;
    const int w = tid >> 6;
    const int colbase = w * (NF * 16);
    const int lg = lane >> 4, li = lane & 15;
    const int row0 = blockIdx.x * 64;

    auto stage = [&](int b, int t) {
#pragma unroll
        for (int j = 0; j < 4; j++) {
            int c_lin = j * 128 + tid;
            int row = c_lin >> 3, c = c_lin & 7;
            int rg = row0 + row;
            if (rg >= N) rg = N - 1;
            int cs = c ^ (row & 7);
            const float* g = X + (size_t)rg * K + t * 32 + cs * 4;
            char* l = (char*)&smemA[b][0] + j * 2048 + w * 1024;
            __builtin_amdgcn_global_load_lds(
                (const __attribute__((address_space(1))) void*)g,
                (__attribute__((address_space(3))) void*)l, 16, 0, 0);
        }
    };

    f32x4 acc[MF][NF];
#pragma unroll
    for (int m = 0; m < MF; m++)
#pragma unroll
        for (int n = 0; n < NF; n++) acc[m][n] = (f32x4){0.f, 0.f, 0.f, 0.f};

    stage(0, 0);
    __syncthreads();

    for (int t = 0; t < NT; t++) {
        const int b = t & 1;
        bf16x8 bh[NF], bl[NF];
        size_t slot0 = (size_t)(t * 4 + lg) * F + colbase + li;
#pragma unroll
        for (int n = 0; n < NF; n++) {
            bh[n] = *(const bf16x8*)(Wh + (slot0 + n * 16) * 8);
            bl[n] = *(const bf16x8*)(Wl + (slot0 + n * 16) * 8);
        }
        __builtin_amdgcn_sched_barrier(0);
        if (t + 1 < NT) stage(b ^ 1, t + 1);
        const float4* lt = &smemA[b][0];
        bf16x8 ah[MF], al[MF];
#pragma unroll
        for (int m = 0; m < MF; m++) {
            int row = m * 16 + li;
            int base = row * 8, sw = row & 7;
            float4 c0 = lt[base + ((2 * lg) ^ sw)];
            float4 c1 = lt[base + ((2 * lg + 1) ^ sw)];
            float xv[8] = {c0.x, c0.y, c0.z, c0.w, c1.x, c1.y, c1.z, c1.w};
            union { u32 u[4]; bf16x8 v; } hi, lo;
#pragma unroll
            for (int q = 0; q < 4; q++) {
                u32 b0 = __float_as_uint(xv[2 * q]);
                u32 b1 = __float_as_uint(xv[2 * q + 1]);
                float l0 = xv[2 * q]     - __uint_as_float(b0 & 0xFFFF0000u);
                float l1 = xv[2 * q + 1] - __uint_as_float(b1 & 0xFFFF0000u);
                hi.u[q] = pack_hi16(b0, b1);
                lo.u[q] = pack_hi16(__float_as_uint(l0), __float_as_uint(l1));
            }
            ah[m] = hi.v;
            al[m] = lo.v;
        }
#pragma unroll
        for (int m = 0; m < MF; m++)
#pragma unroll
            for (int n = 0; n < NF; n++) {
                acc[m][n] = __builtin_amdgcn_mfma_f32_16x16x32_bf16(ah[m], bh[n], acc[m][n], 0, 0, 0);
                acc[m][n] = __builtin_amdgcn_mfma_f32_16x16x32_bf16(ah[m], bl[n], acc[m][n], 0, 0, 0);
                acc[m][n] = __builtin_amdgcn_mfma_f32_16x16x32_bf16(al[m], bh[n], acc[m][n], 0, 0, 0);
            }
        __syncthreads();
    }

#pragma unroll
    for (int m = 0; m < MF; m++) {
        int rb = row0 + m * 16 + lg * 4;
#pragma unroll
        for (int r = 0; r < 4; r++) {
            int gr = rb + r;
            if (gr >= N) continue;
            float di = dinv[gr];
#pragma unroll
            for (int n = 0; n < NF; n++) {
                int col = colbase + n * 16 + li;
                Hh[(size_t)gr * F + col] = __float2half(acc[m][n][r] * di);
            }
        }
    }
}

// --- L2/L3 GEMM body: H'[N,64] = dinv * (Y[N,K] @ W), Y fp16 EXACT -----------
template <int K>
__device__ __forceinline__ void gemm_f16_body(
        const __half* __restrict__ Y,
        const u16* __restrict__ Wh, const u16* __restrict__ Wl,
        const float* __restrict__ dinv, __half* __restrict__ Hh, int N) {
    constexpr int F = 64, MF = 4, NF = 2, NT = K / 32;
    __shared__ float4 smemA[2][256];   // 2 x 4 KB

    const int tid = threadIdx.x;
    const int lane = tid & 63;
    const int w = tid >> 6;
    const int colbase = w * (NF * 16);
    const int lg = lane >> 4, li = lane & 15;
    const int row0 = blockIdx.x * 64;

    auto stage = [&](int b, int t) {
#pragma unroll
        for (int j = 0; j < 2; j++) {
            int c_lin = j * 128 + tid;          // 0..255
            int row = c_lin >> 2, c = c_lin & 3;
            int rg = row0 + row;
            if (rg >= N) rg = N - 1;
            int cs = c ^ (row & 3);
            const __half* g = Y + (size_t)rg * K + t * 32 + cs * 8;  // 16 B
            char* l = (char*)&smemA[b][0] + j * 2048 + w * 1024;
            __builtin_amdgcn_global_load_lds(
                (const __attribute__((address_space(1))) void*)g,
                (__attribute__((address_space(3))) void*)l, 16, 0, 0);
        }
    };

    f32x4 acc[MF][NF];
#pragma unroll
    for (int m = 0; m < MF; m++)
#pragma unroll
        for (int n = 0; n < NF; n++) acc[m][n] = (f32x4){0.f, 0.f, 0.f, 0.f};

    stage(0, 0);
    __syncthreads();

    for (int t = 0; t < NT; t++) {
        const int b = t & 1;
        f16x8 bh[NF], bl[NF];
        size_t slot0 = (size_t)(t * 4 + lg) * F + colbase + li;
#pragma unroll
        for (int n = 0; n < NF; n++) {
            bh[n] = *(const f16x8*)(Wh + (slot0 + n * 16) * 8);
            bl[n] = *(const f16x8*)(Wl + (slot0 + n * 16) * 8);
        }
        __builtin_amdgcn_sched_barrier(0);
        if (t + 1 < NT) stage(b ^ 1, t + 1);
        const float4* lt = &smemA[b][0];
        f16x8 a[MF];
#pragma unroll
        for (int m = 0; m < MF; m++) {
            int row = m * 16 + li;
            union { float4 f; f16x8 h; } u;
            u.f = lt[row * 4 + (lg ^ (row & 3))];
            a[m] = u.h;
        }
#pragma unroll
        for (int m = 0; m < MF; m++)
#pragma unroll
            for (int n = 0; n < NF; n++) {
                acc[m][n] = __builtin_amdgcn_mfma_f32_16x16x32_f16(a[m], bh[n], acc[m][n], 0, 0, 0);
                acc[m][n] = __builtin_amdgcn_mfma_f32_16x16x32_f16(a[m], bl[n], acc[m][n], 0, 0, 0);
            }
        __syncthreads();
    }

#pragma unroll
    for (int m = 0; m < MF; m++) {
        int rb = row0 + m * 16 + lg * 4;
#pragma unroll
        for (int r = 0; r < 4; r++) {
            int gr = rb + r;
            if (gr >= N) continue;
            float di = dinv[gr];
#pragma unroll
            for (int n = 0; n < NF; n++) {
                int col = colbase + n * 16 + li;
                Hh[(size_t)gr * F + col] = __float2half(acc[m][n][r] * di);
            }
        }
    }
}

__global__ __launch_bounds__(128) void k_gemm2(
        const __half* __restrict__ Y, const u16* __restrict__ Wh,
        const u16* __restrict__ Wl, const float* __restrict__ dinv,
        __half* __restrict__ Hh, int N) {
    gemm_f16_body<128>(Y, Wh, Wl, dinv, Hh, N);
}
__global__ __launch_bounds__(128) void k_gemm3(
        const __half* __restrict__ Y, const u16* __restrict__ Wh,
        const u16* __restrict__ Wl, const float* __restrict__ dinv,
        __half* __restrict__ Hh, int N) {
    gemm_f16_body<64>(Y, Wh, Wl, dinv, Hh, N);
}

// --- agg, F=128, fp16 H' in, fp16 y out (leaky-relu); 8-edge unroll -----------
__global__ __launch_bounds__(256) void k_agg128(const __half* __restrict__ Hh,
                                                const int* __restrict__ offs,
                                                const int* __restrict__ csr,
                                                const float* __restrict__ dinv,
                                                const float* __restrict__ bias,
                                                __half* __restrict__ Y, int N) {
    int node = blockIdx.x * 4 + (threadIdx.x >> 6);
    int lane = threadIdx.x & 63;
    if (node >= N) return;
    const __half2* H2 = (const __half2*)Hh;   // row = 64 half2
    float ax = 0.f, ay = 0.f;
    int o0 = offs[node], o1 = offs[node + 1];
    int e = o0;
    for (; e + 8 <= o1; e += 8) {
        int s[8];
#pragma unroll
        for (int q = 0; q < 8; q++) s[q] = csr[e + q];
        float2 f[8];
#pragma unroll
        for (int q = 0; q < 8; q++)
            f[q] = __half22float2(H2[(size_t)s[q] * 64 + lane]);
#pragma unroll
        for (int q = 0; q < 8; q++) { ax += f[q].x; ay += f[q].y; }
    }
    for (; e + 4 <= o1; e += 4) {
        int s0 = csr[e], s1 = csr[e + 1], s2 = csr[e + 2], s3 = csr[e + 3];
        float2 f0 = __half22float2(H2[(size_t)s0 * 64 + lane]);
        float2 f1 = __half22float2(H2[(size_t)s1 * 64 + lane]);
        float2 f2 = __half22float2(H2[(size_t)s2 * 64 + lane]);
        float2 f3 = __half22float2(H2[(size_t)s3 * 64 + lane]);
        ax += (f0.x + f1.x) + (f2.x + f3.x);
        ay += (f0.y + f1.y) + (f2.y + f3.y);
    }
    for (; e < o1; ++e) {
        float2 f0 = __half22float2(H2[(size_t)csr[e] * 64 + lane]);
        ax += f0.x; ay += f0.y;
    }
    float2 fs = __half22float2(H2[(size_t)node * 64 + lane]);
    float di = dinv[node];
    float2 bv = ((const float2*)bias)[lane];
    float vx = di * (ax + fs.x) + bv.x;
    float vy = di * (ay + fs.y) + bv.y;
    vx = vx > 0.f ? vx : 0.2f * vx;
    vy = vy > 0.f ? vy : 0.2f * vy;
    ((__half2*)Y)[(size_t)node * 64 + lane] = __floats2half2_rn(vx, vy);
}

// --- agg, F=64, fp16 H' in — shared body, fp16-y or f32-out; 8-edge unroll ----
template <bool RELU, bool OUT16>
__device__ __forceinline__ void agg64_body(const __half* __restrict__ Hh,
                                           const int* __restrict__ offs,
                                           const int* __restrict__ csr,
                                           const float* __restrict__ dinv,
                                           const float* __restrict__ bias,
                                           void* __restrict__ Y, int N) {
    int node = blockIdx.x * 8 + (threadIdx.x >> 5);
    int lane = threadIdx.x & 31;
    if (node >= N) return;
    const __half2* H2 = (const __half2*)Hh;   // row = 32 half2
    float ax = 0.f, ay = 0.f;
    int o0 = offs[node], o1 = offs[node + 1];
    int e = o0;
    for (; e + 8 <= o1; e += 8) {
        int s[8];
#pragma unroll
        for (int q = 0; q < 8; q++) s[q] = csr[e + q];
        float2 f[8];
#pragma unroll
        for (int q = 0; q < 8; q++)
            f[q] = __half22float2(H2[(size_t)s[q] * 32 + lane]);
#pragma unroll
        for (int q = 0; q < 8; q++) { ax += f[q].x; ay += f[q].y; }
    }
    for (; e + 4 <= o1; e += 4) {
        int s0 = csr[e], s1 = csr[e + 1], s2 = csr[e + 2], s3 = csr[e + 3];
        float2 f0 = __half22float2(H2[(size_t)s0 * 32 + lane]);
        float2 f1 = __half22float2(H2[(size_t)s1 * 32 + lane]);
        float2 f2 = __half22float2(H2[(size_t)s2 * 32 + lane]);
        float2 f3 = __half22float2(H2[(size_t)s3 * 32 + lane]);
        ax += (f0.x + f1.x) + (f2.x + f3.x);
        ay += (f0.y + f1.y) + (f2.y + f3.y);
    }
    for (; e < o1; ++e) {
        float2 f0 = __half22float2(H2[(size_t)csr[e] * 32 + lane]);
        ax += f0.x; ay += f0.y;
    }
    float2 fs = __half22float2(H2[(size_t)node * 32 + lane]);
    float di = dinv[node];
    float2 bv = ((const float2*)bias)[lane];
    float vx = di * (ax + fs.x) + bv.x;
    float vy = di * (ay + fs.y) + bv.y;
    if (RELU) { vx = vx > 0.f ? vx : 0.2f * vx; vy = vy > 0.f ? vy : 0.2f * vy; }
    if (OUT16)
        ((__half2*)Y)[(size_t)node * 32 + lane] = __floats2half2_rn(vx, vy);
    else
        ((float2*)Y)[(size_t)node * 32 + lane] = make_float2(vx, vy);
}

__global__ __launch_bounds__(256) void k_agg64y(const __half* Hh, const int* offs,
                                                const int* csr, const float* dinv,
                                                const float* bias, __half* Y, int N) {
    agg64_body<true, true>(Hh, offs, csr, dinv, bias, Y, N);
}
__global__ __launch_bounds__(256) void k_agg64out(const __half* Hh, const int* offs,
                                                  const int* csr, const float* dinv,
                                                  const float* bias, float* Y, int N) {
    agg64_body<false, false>(Hh, offs, csr, dinv, bias, Y, N);
}

extern "C" void kernel_launch(void* const* d_in, const int* in_sizes, int n_in,
                              void* d_out, int out_size, void* d_ws, size_t ws_size,
                              hipStream_t stream) {
    const float* x  = (const float*)d_in[0];
    const int*   ei = (const int*)d_in[1];
    const float* W1 = (const float*)d_in[2];
    const float* b1 = (const float*)d_in[3];
    const float* W2 = (const float*)d_in[4];
    const float* b2 = (const float*)d_in[5];
    const float* W3 = (const float*)d_in[6];
    const float* b3 = (const float*)d_in[7];

    const int N = in_sizes[0] / 512;
    const int E = in_sizes[1] / 2;
    const int nb = (N + 255) / 256;

    char* w = (char*)d_ws;
    auto take = [&](size_t bytes) -> char* {
        char* p = w;
        w += alignup(bytes, 256);
        return p;
    };
    int*    flag  = (int*)take(256);
    int*    deg   = (int*)take((size_t)N * 4);
    int*    offs  = (int*)take((size_t)(N + 1) * 4);
    int*    bsums = (int*)take((size_t)nb * 4);
    int*    csr   = (int*)take((size_t)E * 4);
    int*    rank  = (int*)take((size_t)E * 4);
    float*  dinv  = (float*)take((size_t)N * 4);
    __half* bufA  = (__half*)take((size_t)N * 128 * 2);   // H' fp16
    __half* bufY  = (__half*)take((size_t)N * 128 * 2);   // y fp16
    u16*    w1h   = (u16*)take((size_t)512 * 128 * 2);
    u16*    w1l   = (u16*)take((size_t)512 * 128 * 2);
    u16*    w2h   = (u16*)take((size_t)128 * 64 * 2);
    u16*    w2l   = (u16*)take((size_t)128 * 64 * 2);
    u16*    w3h   = (u16*)take((size_t)64 * 64 * 2);
    u16*    w3l   = (u16*)take((size_t)64 * 64 * 2);

    const int TB = 256;
    // zero deg (graph-safe async memset), then fused init+deg
    hipMemsetAsync(deg, 0, (size_t)N * 4, stream);
    const int degb = (E + TB - 1) / TB;
    k_init_deg<<<38 + degb, TB, 0, stream>>>(ei, E, flag, deg, rank,
                                             W1, w1h, w1l, W2, w2h, w2l,
                                             W3, w3h, w3l);
    k_scan1<<<nb, 256, 0, stream>>>(deg, offs, bsums, dinv, N);
    k_scan23<<<nb, 256, 0, stream>>>(offs, bsums, nb, N, E);

    const int rowtiles = (N + 63) / 64;
    const int fillblocks = (E + 127) / 128;
    // layer 1 GEMM fused with atomic-free CSR fill (independent work)
    k_gemm1_fill<<<rowtiles + fillblocks, 128, 0, stream>>>(
        x, w1h, w1l, dinv, bufA, N, rowtiles, ei, E, flag, offs, rank, csr);
    k_agg128<<<(N + 3) / 4, 256, 0, stream>>>(bufA, offs, csr, dinv, b1, bufY, N);
    // layer 2
    k_gemm2<<<rowtiles, 128, 0, stream>>>(bufY, w2h, w2l, dinv, bufA, N);
    k_agg64y<<<(N + 7) / 8, 256, 0, stream>>>(bufA, offs, csr, dinv, b2, bufY, N);
    // layer 3
    k_gemm3<<<rowtiles, 128, 0, stream>>>(bufY, w3h, w3l, dinv, bufA, N);
    k_agg64out<<<(N + 7) / 8, 256, 0, stream>>>(bufA, offs, csr, dinv, b3,
                                                (float*)d_out, N);
}

// Round 22
// 181.662 us; speedup vs baseline: 1.3055x; 1.0021x over previous
//
#include <hip/hip_runtime.h>
#include <hip/hip_fp16.h>

// ---------------------------------------------------------------------------
// GCN 3-layer forward on MI355X.  (r22: agg->gemm LDS fusion, layers 2 & 3)
// memset(deg) -> [init: splitW+flag || deg(+rank)] -> scan1(+dinv) -> scan23
//   -> [gemm1 || atomic-free fill] -> [agg128 -> LDS y1 -> gemm2] ->
//   [agg64 -> LDS y2 -> gemm3] -> agg64out          (7 launches + memset)
// r21 insight: fusion is the only overlap/elision tool. gemm2/3 consume
// exactly the rows their agg block produces -> block owns 32 contiguous
// nodes, keeps the y-tile in LDS (chunk-XOR swizzle, <=2-way banks), runs
// the GEMM in-block: kills bufY round-trip (2x12.8MB) + 2 launch gaps.
// ---------------------------------------------------------------------------

typedef __attribute__((ext_vector_type(8))) short bf16x8;
typedef __attribute__((ext_vector_type(8))) _Float16 f16x8;
typedef __attribute__((ext_vector_type(4))) float f32x4;
typedef unsigned short u16;
typedef unsigned int u32;

static inline size_t alignup(size_t v, size_t a) { return (v + a - 1) & ~(a - 1); }

__device__ __forceinline__ u32 pack_hi16(u32 b0, u32 b1) {
    return __builtin_amdgcn_perm(b1, b0, 0x07060302u);   // top16(b0)|top16(b1)
}

// --- W1 split: fragment-ordered bf16 hi/lo -----------------------------------
__device__ __forceinline__ void splitW_bf16(const float* __restrict__ W,
                                            u16* __restrict__ Wh,
                                            u16* __restrict__ Wl, int s, int F) {
    int c = s % F;
    int kb = (s / F) * 8;
    union { u32 u[4]; bf16x8 v; } hi, lo;
#pragma unroll
    for (int p = 0; p < 4; p++) {
        float x0 = W[(size_t)(kb + 2 * p) * F + c];
        float x1 = W[(size_t)(kb + 2 * p + 1) * F + c];
        u32 b0 = __float_as_uint(x0), b1 = __float_as_uint(x1);
        float l0 = x0 - __uint_as_float(b0 & 0xFFFF0000u);
        float l1 = x1 - __uint_as_float(b1 & 0xFFFF0000u);
        hi.u[p] = pack_hi16(b0, b1);
        lo.u[p] = pack_hi16(__float_as_uint(l0), __float_as_uint(l1));
    }
    *(bf16x8*)(Wh + (size_t)s * 8) = hi.v;
    *(bf16x8*)(Wl + (size_t)s * 8) = lo.v;
}

// --- W2/W3 split: fragment-ordered fp16 hi/lo (22-bit effective) -------------
__device__ __forceinline__ void splitW_f16(const float* __restrict__ W,
                                           u16* __restrict__ Wh,
                                           u16* __restrict__ Wl, int s, int F) {
    int c = s % F;
    int kb = (s / F) * 8;
    union { u16 u[8]; bf16x8 v; } hi, lo;
#pragma unroll
    for (int p = 0; p < 8; p++) {
        float xv = W[(size_t)(kb + p) * F + c];
        __half h = __float2half(xv);
        __half l = __float2half(xv - __half2float(h));
        hi.u[p] = __half_as_ushort(h);
        lo.u[p] = __half_as_ushort(l);
    }
    *(bf16x8*)(Wh + (size_t)s * 8) = hi.v;
    *(bf16x8*)(Wl + (size_t)s * 8) = lo.v;
}

// --- FUSED init: splitW+flag blocks [0,38) || deg+rank blocks [38,...) -------
__global__ void k_init_deg(const int* __restrict__ ei, int E,
                           int* __restrict__ flag,
                           int* __restrict__ deg, int* __restrict__ rank,
                           const float* __restrict__ W1, u16* w1h, u16* w1l,
                           const float* __restrict__ W2, u16* w2h, u16* w2l,
                           const float* __restrict__ W3, u16* w3h, u16* w3l) {
    constexpr int SPLITB = 38;                 // 9728/256
    int b = blockIdx.x;
    if (b < SPLITB) {
        if (b == 0 && threadIdx.x < 64) {      // flag for LATER kernels
            int v = ei[2 * threadIdx.x + 1];
            unsigned long long m = __ballot(v != 0);
            if (threadIdx.x == 0) *flag = (m == 0ull) ? 1 : 0;
        }
        int s = b * 256 + threadIdx.x;
        if (s < 8192) splitW_bf16(W1, w1h, w1l, s, 128);           // 512x128/8
        else if (s < 9216) splitW_f16(W2, w2h, w2l, s - 8192, 64); // 128x64/8
        else if (s < 9728) splitW_f16(W3, w3h, w3l, s - 9216, 64); // 64x64/8
        return;
    }
    // per-wave layout detect (identical result in every wave, race-free)
    int v = ei[2 * (threadIdx.x & 63) + 1];
    unsigned long long m = __ballot(v != 0);
    int is64 = (m == 0ull) ? 1 : 0;
    int i = (b - SPLITB) * 256 + threadIdx.x;
    if (i >= E) return;
    int d = is64 ? ei[2 * (E + i)] : ei[E + i];
    rank[i] = atomicAdd(&deg[d], 1);           // return value = edge rank
}

__global__ void k_scan1(const int* __restrict__ deg, int* __restrict__ offs,
                        int* __restrict__ bsums, float* __restrict__ dinv, int N) {
    __shared__ int s[256];
    int i = blockIdx.x * 256 + threadIdx.x;
    int v = (i < N) ? deg[i] : 0;
    if (i < N) dinv[i] = rsqrtf((float)v + 1.0f);
    s[threadIdx.x] = v;
    __syncthreads();
    for (int off = 1; off < 256; off <<= 1) {
        int t = (threadIdx.x >= off) ? s[threadIdx.x - off] : 0;
        __syncthreads();
        s[threadIdx.x] += t;
        __syncthreads();
    }
    if (i < N) offs[i] = s[threadIdx.x] - v;   // exclusive
    if (threadIdx.x == 255) bsums[blockIdx.x] = s[255];
}

__global__ void k_scan23(int* __restrict__ offs, const int* __restrict__ bsums,
                         int nb, int N, int E) {
    __shared__ int s[256];
    int tid = threadIdx.x;
    s[tid] = (tid < nb) ? bsums[tid] : 0;
    __syncthreads();
    for (int off = 1; off < 256; off <<= 1) {
        int t = (tid >= off) ? s[tid - off] : 0;
        __syncthreads();
        s[tid] += t;                 // inclusive scan
        __syncthreads();
    }
    int boff = (blockIdx.x > 0) ? s[blockIdx.x - 1] : 0;
    int i = blockIdx.x * 256 + tid;
    if (i < N) offs[i] += boff;
    if (i == 0) offs[N] = E;
}

// --- FUSED: gemm1 blocks [0,rowtiles) || atomic-free fill blocks -------------
__global__ __launch_bounds__(128) void k_gemm1_fill(
        const float* __restrict__ X,
        const u16* __restrict__ Wh, const u16* __restrict__ Wl,
        const float* __restrict__ dinv, __half* __restrict__ Hh, int N,
        int rowtiles,
        const int* __restrict__ ei, int E, const int* __restrict__ flag,
        const int* __restrict__ offs, const int* __restrict__ rank,
        int* __restrict__ csr) {
    constexpr int K = 512, F = 128, MF = 4, NF = 4, NT = K / 32;
    __shared__ float4 smemA[2][512];   // 2 x 8 KB (gemm path only)

    if ((int)blockIdx.x >= rowtiles) {
        int i = ((int)blockIdx.x - rowtiles) * 128 + threadIdx.x;
        if (i < E) {
            int is64 = *flag;
            int s = is64 ? ei[2 * i] : ei[i];
            int d = is64 ? ei[2 * (E + i)] : ei[E + i];
            csr[offs[d] + rank[i]] = s;
        }
        return;
    }

    const int tid = threadIdx.x;
    const int lane = tid & 63;
    const int w = tid >> 6;
    const int colbase = w * (NF * 16);
    const int lg = lane >> 4, li = lane & 15;
    const int row0 = blockIdx.x * 64;

    auto stage = [&](int b, int t) {
#pragma unroll
        for (int j = 0; j < 4; j++) {
            int c_lin = j * 128 + tid;
            int row = c_lin >> 3, c = c_lin & 7;
            int rg = row0 + row;
            if (rg >= N) rg = N - 1;
            int cs = c ^ (row & 7);
            const float* g = X + (size_t)rg * K + t * 32 + cs * 4;
            char* l = (char*)&smemA[b][0] + j * 2048 + w * 1024;
            __builtin_amdgcn_global_load_lds(
                (const __attribute__((address_space(1))) void*)g,
                (__attribute__((address_space(3))) void*)l, 16, 0, 0);
        }
    };

    f32x4 acc[MF][NF];
#pragma unroll
    for (int m = 0; m < MF; m++)
#pragma unroll
        for (int n = 0; n < NF; n++) acc[m][n] = (f32x4){0.f, 0.f, 0.f, 0.f};

    stage(0, 0);
    __syncthreads();

    for (int t = 0; t < NT; t++) {
        const int b = t & 1;
        bf16x8 bh[NF], bl[NF];
        size_t slot0 = (size_t)(t * 4 + lg) * F + colbase + li;
#pragma unroll
        for (int n = 0; n < NF; n++) {
            bh[n] = *(const bf16x8*)(Wh + (slot0 + n * 16) * 8);
            bl[n] = *(const bf16x8*)(Wl + (slot0 + n * 16) * 8);
        }
        __builtin_amdgcn_sched_barrier(0);
        if (t + 1 < NT) stage(b ^ 1, t + 1);
        const float4* lt = &smemA[b][0];
        bf16x8 ah[MF], al[MF];
#pragma unroll
        for (int m = 0; m < MF; m++) {
            int row = m * 16 + li;
            int base = row * 8, sw = row & 7;
            float4 c0 = lt[base + ((2 * lg) ^ sw)];
            float4 c1 = lt[base + ((2 * lg + 1) ^ sw)];
            float xv[8] = {c0.x, c0.y, c0.z, c0.w, c1.x, c1.y, c1.z, c1.w};
            union { u32 u[4]; bf16x8 v; } hi, lo;
#pragma unroll
            for (int q = 0; q < 4; q++) {
                u32 b0 = __float_as_uint(xv[2 * q]);
                u32 b1 = __float_as_uint(xv[2 * q + 1]);
                float l0 = xv[2 * q]     - __uint_as_float(b0 & 0xFFFF0000u);
                float l1 = xv[2 * q + 1] - __uint_as_float(b1 & 0xFFFF0000u);
                hi.u[q] = pack_hi16(b0, b1);
                lo.u[q] = pack_hi16(__float_as_uint(l0), __float_as_uint(l1));
            }
            ah[m] = hi.v;
            al[m] = lo.v;
        }
#pragma unroll
        for (int m = 0; m < MF; m++)
#pragma unroll
            for (int n = 0; n < NF; n++) {
                acc[m][n] = __builtin_amdgcn_mfma_f32_16x16x32_bf16(ah[m], bh[n], acc[m][n], 0, 0, 0);
                acc[m][n] = __builtin_amdgcn_mfma_f32_16x16x32_bf16(ah[m], bl[n], acc[m][n], 0, 0, 0);
                acc[m][n] = __builtin_amdgcn_mfma_f32_16x16x32_bf16(al[m], bh[n], acc[m][n], 0, 0, 0);
            }
        __syncthreads();
    }

#pragma unroll
    for (int m = 0; m < MF; m++) {
        int rb = row0 + m * 16 + lg * 4;
#pragma unroll
        for (int r = 0; r < 4; r++) {
            int gr = rb + r;
            if (gr >= N) continue;
            float di = dinv[gr];
#pragma unroll
            for (int n = 0; n < NF; n++) {
                int col = colbase + n * 16 + li;
                Hh[(size_t)gr * F + col] = __float2half(acc[m][n][r] * di);
            }
        }
    }
}

// --- FUSED layer 2: agg128 -> y1 tile in LDS -> gemm2 -> H'2 fp16 ------------
// Block owns 32 contiguous nodes; 256 thr = 4 waves.
// Phase A: wave w gathers nodes node0+w*8..+7 (full-wave rows, 8-edge unroll),
//   y row -> LDS chunk-swizzled (chunk c' = c ^ (r&15); <=2-way banks).
// Phase B: gemm2 from LDS: wave = (row half 16) x (col half 32), K=128.
__global__ __launch_bounds__(256) void k_agg1_gemm2(
        const __half* __restrict__ Hh, const int* __restrict__ offs,
        const int* __restrict__ csr, const float* __restrict__ dinv,
        const float* __restrict__ bias,
        const u16* __restrict__ Wh, const u16* __restrict__ Wl,
        __half* __restrict__ Out, int N) {
    __shared__ float4 ytile[512];                 // 32 rows x 16 chunks = 8 KB
    __half2* yh2 = (__half2*)ytile;               // [r*64 + c'*4 + pos]

    const int tid = threadIdx.x;
    const int lane = tid & 63;
    const int w = tid >> 6;
    const int node0 = blockIdx.x * 32;
    const __half2* H2 = (const __half2*)Hh;       // H'1 row = 64 half2

    // ---- Phase A: aggregate 8 nodes per wave ----
#pragma unroll 1
    for (int q = 0; q < 8; q++) {
        int r = w * 8 + q;
        int node = node0 + r;
        if (node < N) {
            float ax = 0.f, ay = 0.f;
            int o0 = offs[node], o1 = offs[node + 1];
            int e = o0;
            for (; e + 8 <= o1; e += 8) {
                int s[8];
#pragma unroll
                for (int p = 0; p < 8; p++) s[p] = csr[e + p];
                float2 f[8];
#pragma unroll
                for (int p = 0; p < 8; p++)
                    f[p] = __half22float2(H2[(size_t)s[p] * 64 + lane]);
#pragma unroll
                for (int p = 0; p < 8; p++) { ax += f[p].x; ay += f[p].y; }
            }
            for (; e < o1; ++e) {
                float2 f0 = __half22float2(H2[(size_t)csr[e] * 64 + lane]);
                ax += f0.x; ay += f0.y;
            }
            float2 fs = __half22float2(H2[(size_t)node * 64 + lane]);
            float di = dinv[node];
            float2 bv = ((const float2*)bias)[lane];
            float vx = di * (ax + fs.x) + bv.x;
            float vy = di * (ay + fs.y) + bv.y;
            vx = vx > 0.f ? vx : 0.2f * vx;
            vy = vy > 0.f ? vy : 0.2f * vy;
            int c = lane >> 2, pos = lane & 3;
            int cc = c ^ (r & 15);
            yh2[r * 64 + cc * 4 + pos] = __floats2half2_rn(vx, vy);
        }
    }
    __syncthreads();

    // ---- Phase B: gemm2 (y1[32,128] @ W2[128,64]) from LDS ----
    constexpr int NF = 2, NT = 4, F = 64;
    const int wr = (w >> 1) * 16;                 // row half
    const int wc = (w & 1) * 32;                  // col half
    const int lg = lane >> 4, li = lane & 15;

    f32x4 acc[NF];
#pragma unroll
    for (int n = 0; n < NF; n++) acc[n] = (f32x4){0.f, 0.f, 0.f, 0.f};

#pragma unroll
    for (int t = 0; t < NT; t++) {
        f16x8 bh[NF], bl[NF];
        size_t slot0 = (size_t)(t * 4 + lg) * F + wc + li;
#pragma unroll
        for (int n = 0; n < NF; n++) {
            bh[n] = *(const f16x8*)(Wh + (slot0 + n * 16) * 8);
            bl[n] = *(const f16x8*)(Wl + (slot0 + n * 16) * 8);
        }
        int r = wr + li;                          // r&15 == li
        int c = t * 4 + lg;
        union { float4 f; f16x8 h; } u;
        u.f = ytile[r * 16 + (c ^ li)];
        f16x8 a = u.h;
#pragma unroll
        for (int n = 0; n < NF; n++) {
            acc[n] = __builtin_amdgcn_mfma_f32_16x16x32_f16(a, bh[n], acc[n], 0, 0, 0);
            acc[n] = __builtin_amdgcn_mfma_f32_16x16x32_f16(a, bl[n], acc[n], 0, 0, 0);
        }
    }

#pragma unroll
    for (int rr = 0; rr < 4; rr++) {
        int gr = node0 + wr + lg * 4 + rr;
        if (gr >= N) continue;
        float di = dinv[gr];
#pragma unroll
        for (int n = 0; n < NF; n++) {
            int col = wc + n * 16 + li;
            Out[(size_t)gr * F + col] = __float2half(acc[n][rr] * di);
        }
    }
}

// --- FUSED layer 3: agg64 -> y2 tile in LDS -> gemm3 -> H'3 fp16 -------------
// Block owns 32 nodes. Phase A: half-wave per node (row = 32 half2),
// chunk swizzle c' = c ^ (r&7). Phase B: gemm3 K=64 from LDS.
__global__ __launch_bounds__(256) void k_agg2_gemm3(
        const __half* __restrict__ Hh, const int* __restrict__ offs,
        const int* __restrict__ csr, const float* __restrict__ dinv,
        const float* __restrict__ bias,
        const u16* __restrict__ Wh, const u16* __restrict__ Wl,
        __half* __restrict__ Out, int N) {
    __shared__ float4 ytile[256];                 // 32 rows x 8 chunks = 4 KB
    __half2* yh2 = (__half2*)ytile;               // [r*32 + c'*4 + pos]

    const int tid = threadIdx.x;
    const int lane = tid & 63;
    const int w = tid >> 6;
    const int node0 = blockIdx.x * 32;
    const __half2* H2 = (const __half2*)Hh;       // H'2 row = 32 half2

    // ---- Phase A: 8 nodes per wave, 2 per iteration (half-waves) ----
#pragma unroll 1
    for (int q = 0; q < 4; q++) {
        int r = w * 8 + q * 2 + (lane >> 5);
        int node = node0 + r;
        int l = lane & 31;
        if (node < N) {
            float ax = 0.f, ay = 0.f;
            int o0 = offs[node], o1 = offs[node + 1];
            int e = o0;
            for (; e + 8 <= o1; e += 8) {
                int s[8];
#pragma unroll
                for (int p = 0; p < 8; p++) s[p] = csr[e + p];
                float2 f[8];
#pragma unroll
                for (int p = 0; p < 8; p++)
                    f[p] = __half22float2(H2[(size_t)s[p] * 32 + l]);
#pragma unroll
                for (int p = 0; p < 8; p++) { ax += f[p].x; ay += f[p].y; }
            }
            for (; e < o1; ++e) {
                float2 f0 = __half22float2(H2[(size_t)csr[e] * 32 + l]);
                ax += f0.x; ay += f0.y;
            }
            float2 fs = __half22float2(H2[(size_t)node * 32 + l]);
            float di = dinv[node];
            float2 bv = ((const float2*)bias)[l];
            float vx = di * (ax + fs.x) + bv.x;
            float vy = di * (ay + fs.y) + bv.y;
            vx = vx > 0.f ? vx : 0.2f * vx;
            vy = vy > 0.f ? vy : 0.2f * vy;
            int c = l >> 2, pos = l & 3;
            int cc = c ^ (r & 7);
            yh2[r * 32 + cc * 4 + pos] = __floats2half2_rn(vx, vy);
        }
    }
    __syncthreads();

    // ---- Phase B: gemm3 (y2[32,64] @ W3[64,64]) from LDS ----
    constexpr int NF = 2, NT = 2, F = 64;
    const int wr = (w >> 1) * 16;
    const int wc = (w & 1) * 32;
    const int lg = lane >> 4, li = lane & 15;

    f32x4 acc[NF];
#pragma unroll
    for (int n = 0; n < NF; n++) acc[n] = (f32x4){0.f, 0.f, 0.f, 0.f};

#pragma unroll
    for (int t = 0; t < NT; t++) {
        f16x8 bh[NF], bl[NF];
        size_t slot0 = (size_t)(t * 4 + lg) * F + wc + li;
#pragma unroll
        for (int n = 0; n < NF; n++) {
            bh[n] = *(const f16x8*)(Wh + (slot0 + n * 16) * 8);
            bl[n] = *(const f16x8*)(Wl + (slot0 + n * 16) * 8);
        }
        int r = wr + li;                          // r&7 == li&7
        int c = t * 4 + lg;                       // 0..7
        union { float4 f; f16x8 h; } u;
        u.f = ytile[r * 8 + (c ^ (li & 7))];
        f16x8 a = u.h;
#pragma unroll
        for (int n = 0; n < NF; n++) {
            acc[n] = __builtin_amdgcn_mfma_f32_16x16x32_f16(a, bh[n], acc[n], 0, 0, 0);
            acc[n] = __builtin_amdgcn_mfma_f32_16x16x32_f16(a, bl[n], acc[n], 0, 0, 0);
        }
    }

#pragma unroll
    for (int rr = 0; rr < 4; rr++) {
        int gr = node0 + wr + lg * 4 + rr;
        if (gr >= N) continue;
        float di = dinv[gr];
#pragma unroll
        for (int n = 0; n < NF; n++) {
            int col = wc + n * 16 + li;
            Out[(size_t)gr * F + col] = __float2half(acc[n][rr] * di);
        }
    }
}

// --- final agg, F=64, fp16 H'3 in, f32 out (no relu); 8-edge unroll ----------
__global__ __launch_bounds__(256) void k_agg64out(const __half* __restrict__ Hh,
                                                  const int* __restrict__ offs,
                                                  const int* __restrict__ csr,
                                                  const float* __restrict__ dinv,
                                                  const float* __restrict__ bias,
                                                  float* __restrict__ Y, int N) {
    int node = blockIdx.x * 8 + (threadIdx.x >> 5);
    int lane = threadIdx.x & 31;
    if (node >= N) return;
    const __half2* H2 = (const __half2*)Hh;   // row = 32 half2
    float ax = 0.f, ay = 0.f;
    int o0 = offs[node], o1 = offs[node + 1];
    int e = o0;
    for (; e + 8 <= o1; e += 8) {
        int s[8];
#pragma unroll
        for (int q = 0; q < 8; q++) s[q] = csr[e + q];
        float2 f[8];
#pragma unroll
        for (int q = 0; q < 8; q++)
            f[q] = __half22float2(H2[(size_t)s[q] * 32 + lane]);
#pragma unroll
        for (int q = 0; q < 8; q++) { ax += f[q].x; ay += f[q].y; }
    }
    for (; e + 4 <= o1; e += 4) {
        int s0 = csr[e], s1 = csr[e + 1], s2 = csr[e + 2], s3 = csr[e + 3];
        float2 f0 = __half22float2(H2[(size_t)s0 * 32 + lane]);
        float2 f1 = __half22float2(H2[(size_t)s1 * 32 + lane]);
        float2 f2 = __half22float2(H2[(size_t)s2 * 32 + lane]);
        float2 f3 = __half22float2(H2[(size_t)s3 * 32 + lane]);
        ax += (f0.x + f1.x) + (f2.x + f3.x);
        ay += (f0.y + f1.y) + (f2.y + f3.y);
    }
    for (; e < o1; ++e) {
        float2 f0 = __half22float2(H2[(size_t)csr[e] * 32 + lane]);
        ax += f0.x; ay += f0.y;
    }
    float2 fs = __half22float2(H2[(size_t)node * 32 + lane]);
    float di = dinv[node];
    float2 bv = ((const float2*)bias)[lane];
    float vx = di * (ax + fs.x) + bv.x;
    float vy = di * (ay + fs.y) + bv.y;
    ((float2*)Y)[(size_t)node * 32 + lane] = make_float2(vx, vy);
}

extern "C" void kernel_launch(void* const* d_in, const int* in_sizes, int n_in,
                              void* d_out, int out_size, void* d_ws, size_t ws_size,
                              hipStream_t stream) {
    const float* x  = (const float*)d_in[0];
    const int*   ei = (const int*)d_in[1];
    const float* W1 = (const float*)d_in[2];
    const float* b1 = (const float*)d_in[3];
    const float* W2 = (const float*)d_in[4];
    const float* b2 = (const float*)d_in[5];
    const float* W3 = (const float*)d_in[6];
    const float* b3 = (const float*)d_in[7];

    const int N = in_sizes[0] / 512;
    const int E = in_sizes[1] / 2;
    const int nb = (N + 255) / 256;

    char* w = (char*)d_ws;
    auto take = [&](size_t bytes) -> char* {
        char* p = w;
        w += alignup(bytes, 256);
        return p;
    };
    int*    flag  = (int*)take(256);
    int*    deg   = (int*)take((size_t)N * 4);
    int*    offs  = (int*)take((size_t)(N + 1) * 4);
    int*    bsums = (int*)take((size_t)nb * 4);
    int*    csr   = (int*)take((size_t)E * 4);
    int*    rank  = (int*)take((size_t)E * 4);
    float*  dinv  = (float*)take((size_t)N * 4);
    __half* bufA  = (__half*)take((size_t)N * 128 * 2);   // H'1 / H'3
    __half* bufB  = (__half*)take((size_t)N * 128 * 2);   // H'2
    u16*    w1h   = (u16*)take((size_t)512 * 128 * 2);
    u16*    w1l   = (u16*)take((size_t)512 * 128 * 2);
    u16*    w2h   = (u16*)take((size_t)128 * 64 * 2);
    u16*    w2l   = (u16*)take((size_t)128 * 64 * 2);
    u16*    w3h   = (u16*)take((size_t)64 * 64 * 2);
    u16*    w3l   = (u16*)take((size_t)64 * 64 * 2);

    const int TB = 256;
    // zero deg (graph-safe async memset), then fused init+deg
    hipMemsetAsync(deg, 0, (size_t)N * 4, stream);
    const int degb = (E + TB - 1) / TB;
    k_init_deg<<<38 + degb, TB, 0, stream>>>(ei, E, flag, deg, rank,
                                             W1, w1h, w1l, W2, w2h, w2l,
                                             W3, w3h, w3l);
    k_scan1<<<nb, 256, 0, stream>>>(deg, offs, bsums, dinv, N);
    k_scan23<<<nb, 256, 0, stream>>>(offs, bsums, nb, N, E);

    const int rowtiles = (N + 63) / 64;
    const int fillblocks = (E + 127) / 128;
    const int fuseblocks = (N + 31) / 32;
    // layer 1 GEMM fused with atomic-free CSR fill (independent work)
    k_gemm1_fill<<<rowtiles + fillblocks, 128, 0, stream>>>(
        x, w1h, w1l, dinv, bufA, N, rowtiles, ei, E, flag, offs, rank, csr);
    // layer 2: agg128 -> LDS y1 -> gemm2 (H'2 into bufB)
    k_agg1_gemm2<<<fuseblocks, 256, 0, stream>>>(bufA, offs, csr, dinv, b1,
                                                 w2h, w2l, bufB, N);
    // layer 3: agg64 -> LDS y2 -> gemm3 (H'3 into bufA, dead after phase A)
    k_agg2_gemm3<<<fuseblocks, 256, 0, stream>>>(bufB, offs, csr, dinv, b2,
                                                 w3h, w3l, bufA, N);
    // final aggregation straight to output
    k_agg64out<<<(N + 7) / 8, 256, 0, stream>>>(bufA, offs, csr, dinv, b3,
                                                (float*)d_out, N);
}